// Round 7
// baseline (864.012 us; speedup 1.0000x reference)
//
#include <hip/hip_runtime.h>
#include <cstddef>

// ---------------------------------------------------------------------------
// SegTransformerDecoder — round 7.
//  * conv1_f32 v3: 2-wave blocks, 128x64 tile, conflict-free LDS reads
//    (og=t>>3 broadcast As, pg=t&7 2-way Bs), grid 1000 blocks.
//  * sample_k2: 4 independent tap accumulators (ILP), bf16 feature taps.
// ---------------------------------------------------------------------------

#define HW   10000
#define WID  100

typedef __attribute__((ext_vector_type(8))) __bf16 bf16x8;
typedef __attribute__((ext_vector_type(4))) float f32x4;
typedef __attribute__((ext_vector_type(4))) unsigned int uint4v;

__device__ __forceinline__ float gelu_exact(float x) {
    return 0.5f * x * (1.0f + erff(x * 0.7071067811865475f));
}
__device__ __forceinline__ unsigned short f2bf(float v) {
    unsigned int b = __float_as_uint(v);
    return (unsigned short)((b + 0x7FFFu + ((b >> 16) & 1u)) >> 16);
}
__device__ __forceinline__ float bf2f(short s) {
    return __uint_as_float(((unsigned int)(unsigned short)s) << 16);
}
__device__ __forceinline__ bf16x8 load_frag(const short* p) {
    return __builtin_bit_cast(bf16x8, *(const uint4v*)p);
}

// ---------------------------------------------------------------------------
// conv1_f32 v3 (decision chain, exact fp32; same summation order as r6).
// input xpadP: channel-major padded(2) [128][104][104] fp32
// weights wpkf: [ky][kx][ic][oc] fp32
// block 128 thr (2 waves), tile 128oc x 64pix (2 rows x 32 cols),
// thread = 8oc x 8pix, og=t>>3, pg=t&7.  grid (4, 50, 5); z = ky.
// ---------------------------------------------------------------------------
__global__ __launch_bounds__(128)
void conv1_f32(const float* __restrict__ wpkf, const float* __restrict__ xpadP,
               float* __restrict__ slab)
{
    __shared__ float As[2048];      // [ic 16][oc 128]
    __shared__ float Bs[1024];      // [ic 16][pix 64]
    const int t  = threadIdx.x;
    const int og = t >> 3;          // 16 groups of 8 oc
    const int pg = t & 7;           // 8 groups of 8 pix
    const int x0 = blockIdx.x * 32, y0 = blockIdx.y * 2;
    const int ky = blockIdx.z;

    // Bs staging: 1024 floats, 2 passes of 128 x float4
    const int be0 = t * 4, be1 = 512 + t * 4;
    const int ic_b0 = be0 >> 6, p_b0 = be0 & 63;
    const int ic_b1 = be1 >> 6, p_b1 = be1 & 63;
    const int row_b0 = (y0 + (p_b0 >> 5) + ky) * 104 + x0 + (p_b0 & 31);
    const int row_b1 = (y0 + (p_b1 >> 5) + ky) * 104 + x0 + (p_b1 & 31);

    float acc[8][8];
#pragma unroll
    for (int i = 0; i < 8; ++i)
#pragma unroll
        for (int j = 0; j < 8; ++j) acc[i][j] = 0.f;

    for (int kx = 0; kx < 5; ++kx) {
        for (int ic0 = 0; ic0 < 128; ic0 += 16) {
            __syncthreads();
            const float* asrc = wpkf + (size_t)((ky * 5 + kx) * 128 + ic0) * 128;
#pragma unroll
            for (int c = 0; c < 4; ++c)
                *(float4*)(As + t * 4 + c * 512) = *(const float4*)(asrc + t * 4 + c * 512);
            float4 bv0, bv1;
            __builtin_memcpy(&bv0, xpadP + (size_t)(ic0 + ic_b0) * 10816 + row_b0 + kx, 16);
            __builtin_memcpy(&bv1, xpadP + (size_t)(ic0 + ic_b1) * 10816 + row_b1 + kx, 16);
            *(float4*)(Bs + be0) = bv0;
            *(float4*)(Bs + be1) = bv1;
            __syncthreads();
#pragma unroll
            for (int k = 0; k < 16; ++k) {
                float a[8], b[8];
                *(float4*)(a)     = *(float4*)(As + k * 128 + og * 8);
                *(float4*)(a + 4) = *(float4*)(As + k * 128 + og * 8 + 4);
                *(float4*)(b)     = *(float4*)(Bs + k * 64 + pg * 8);
                *(float4*)(b + 4) = *(float4*)(Bs + k * 64 + pg * 8 + 4);
#pragma unroll
                for (int i = 0; i < 8; ++i)
#pragma unroll
                    for (int j = 0; j < 8; ++j)
                        acc[i][j] = fmaf(a[i], b[j], acc[i][j]);
            }
        }
    }

    // epilogue: thread owns 8 consecutive pixels of one row, for 8 oc
    float* sl = slab + (size_t)ky * 1280000;
    const int py = y0 + (pg >> 2);
    const int px = x0 + (pg & 3) * 8;
    if (px >= 100) return;
#pragma unroll
    for (int i = 0; i < 8; ++i) {
        float* dst = sl + (size_t)(og * 8 + i) * HW + py * WID + px;
        if (px + 8 <= 100) {
            __builtin_memcpy(dst,     &acc[i][0], 16);
            __builtin_memcpy(dst + 4, &acc[i][4], 16);
        } else {
#pragma unroll
            for (int j = 0; j < 8; ++j)
                if (px + j < 100) dst[j] = acc[i][j];
        }
    }
}

// ---------------------------------------------------------------------------
// bf16 MFMA implicit-GEMM conv, 128oc x 128pix block tile (unchanged).
// ---------------------------------------------------------------------------
template<int CIN, int KS, int COUT, int EPI, bool ACT, int OPAD, int OPW, int KSPLIT>
__global__ __launch_bounds__(256)
void mfma_conv(const short* __restrict__ wpk, const short* __restrict__ xcl,
               const float* __restrict__ bias,
               float* __restrict__ outcm, short* __restrict__ outcl)
{
    constexpr int PW = 100 + 2 * (KS / 2);
    constexpr int CHUNK = (KS + KSPLIT - 1) / KSPLIT;
    const int lane = threadIdx.x & 63;
    const int wave = threadIdx.x >> 6;
    const int wr = wave >> 1;
    const int wc = wave & 1;
    const int lq = lane >> 4;
    const int ln = lane & 15;

    const int oc0 = blockIdx.x * 128;
    const int y0  = blockIdx.y * 4;
    const int zb  = blockIdx.z;
    const int bx  = (KSPLIT > 1) ? (zb & 3) : zb;
    const int ks  = (KSPLIT > 1) ? (zb >> 2) : 0;
    const int x0  = bx * 32;
    const int ky_lo = ks * CHUNK;
    const int ky_hi = (ky_lo + CHUNK < KS) ? ky_lo + CHUNK : KS;

    int bpix[4];
#pragma unroll
    for (int nt = 0; nt < 4; ++nt) {
        const int nl = wc * 64 + nt * 16 + ln;
        bpix[nt] = (y0 + (nl >> 5)) * PW + (x0 + (nl & 31));
    }

    f32x4 acc[4][4];
#pragma unroll
    for (int mt = 0; mt < 4; ++mt)
#pragma unroll
        for (int nt = 0; nt < 4; ++nt)
#pragma unroll
            for (int r = 0; r < 4; ++r) acc[mt][nt][r] = 0.f;

    const int arow0 = oc0 + wr * 64 + ln;

    for (int ky = ky_lo; ky < ky_hi; ++ky) {
#pragma unroll
        for (int kx = 0; kx < KS; ++kx) {
            const short* wsl = wpk + (size_t)((ky * KS + kx) * COUT) * CIN;
            const short* xsl = xcl + (size_t)(ky * PW + kx) * CIN;
            for (int ic0 = 0; ic0 < CIN; ic0 += 32) {
                bf16x8 a[4], b[4];
#pragma unroll
                for (int mt = 0; mt < 4; ++mt)
                    a[mt] = load_frag(wsl + (size_t)(arow0 + mt * 16) * CIN + ic0 + lq * 8);
#pragma unroll
                for (int nt = 0; nt < 4; ++nt)
                    b[nt] = load_frag(xsl + (size_t)bpix[nt] * CIN + ic0 + lq * 8);
#pragma unroll
                for (int mt = 0; mt < 4; ++mt)
#pragma unroll
                    for (int nt = 0; nt < 4; ++nt)
                        acc[mt][nt] = __builtin_amdgcn_mfma_f32_16x16x32_bf16(
                            a[mt], b[nt], acc[mt][nt], 0, 0, 0);
            }
        }
    }

#pragma unroll
    for (int mt = 0; mt < 4; ++mt) {
        const int ocr = oc0 + wr * 64 + mt * 16 + lq * 4;
        float bb[4];
        if (EPI == 1) {
            const float4 bv = *(const float4*)(bias + ocr);
            bb[0] = bv.x; bb[1] = bv.y; bb[2] = bv.z; bb[3] = bv.w;
        }
#pragma unroll
        for (int nt = 0; nt < 4; ++nt) {
            const int nl = wc * 64 + nt * 16 + ln;
            const int x = x0 + (nl & 31);
            const int y = y0 + (nl >> 5);
            if (x >= 100) continue;
            if (EPI == 1) {
                float v[4];
#pragma unroll
                for (int r = 0; r < 4; ++r) {
                    float t = acc[mt][nt][r] + bb[r];
                    if (ACT) t = gelu_exact(t);
                    v[r] = t;
                }
                ushort4 pk;
                pk.x = f2bf(v[0]); pk.y = f2bf(v[1]); pk.z = f2bf(v[2]); pk.w = f2bf(v[3]);
                *(ushort4*)(outcl + ((size_t)(y + OPAD) * OPW + (x + OPAD)) * COUT + ocr) = pk;
            } else {
                const int pix = y * WID + x;
#pragma unroll
                for (int r = 0; r < 4; ++r)
                    outcm[((size_t)ks * COUT + ocr + r) * HW + pix] = acc[mt][nt][r];
            }
        }
    }
}

// fused: out = inorm(bias + res + sum_z slab[z])
template<int NS>
__global__ __launch_bounds__(256)
void red_norm_k(const float* __restrict__ bias, const float* __restrict__ res,
                const float* __restrict__ slab, float* __restrict__ outp)
{
    const int c = blockIdx.x, tid = threadIdx.x;
    const size_t base = (size_t)c * HW;
    const float bc = bias[c];
    float v[40];
    float s1 = 0.f, s2 = 0.f;
#pragma unroll
    for (int k = 0; k < 40; ++k) {
        const int i = tid + k * 256;
        float x = 0.f;
        if (i < HW) {
            x = bc + res[base + i];
#pragma unroll
            for (int z = 0; z < NS; ++z) x += slab[(size_t)z * 1280000 + base + i];
            s1 += x; s2 += x * x;
        }
        v[k] = x;
    }
    __shared__ float r1[256], r2[256];
    r1[tid] = s1; r2[tid] = s2; __syncthreads();
    for (int o = 128; o > 0; o >>= 1) {
        if (tid < o) { r1[tid] += r1[tid + o]; r2[tid] += r2[tid + o]; }
        __syncthreads();
    }
    const float mean = r1[0] * 1e-4f;
    const float var  = fmaxf(r2[0] * 1e-4f - mean * mean, 0.f);
    const float rstd = rsqrtf(var + 1e-5f);
#pragma unroll
    for (int k = 0; k < 40; ++k) {
        const int i = tid + k * 256;
        if (i < HW) outp[base + i] = (v[k] - mean) * rstd;
    }
}

// fp32 channel-major [128][100][100] -> channel-major padded(2) [128][104][104]
__global__ void pad_xpad(const float* __restrict__ in, float* __restrict__ out)
{
    const int total = 128 * 104 * 104;
    for (int i = blockIdx.x * blockDim.x + threadIdx.x; i < total; i += gridDim.x * blockDim.x) {
        const int c = i / 10816;
        const int r = i % 10816;
        const int y = r / 104 - 2;
        const int x = r % 104 - 2;
        float v = 0.f;
        if (x >= 0 && x < 100 && y >= 0 && y < 100) v = in[(size_t)c * HW + y * WID + x];
        out[i] = v;
    }
}

template<int C, int PAD>
__global__ void pad_cl_cast(const float* __restrict__ in, short* __restrict__ out)
{
    constexpr int PW = 100 + 2 * PAD;
    const int total = PW * PW * C;
    for (int i = blockIdx.x * blockDim.x + threadIdx.x; i < total; i += gridDim.x * blockDim.x) {
        const int c = i % C;
        const int p = i / C;
        const int x = p % PW - PAD;
        const int y = p / PW - PAD;
        float v = 0.f;
        if (x >= 0 && x < 100 && y >= 0 && y < 100) v = in[(size_t)c * HW + y * WID + x];
        out[i] = (short)f2bf(v);
    }
}

__global__ void pack_all_bf16(const float* __restrict__ w1, const float* __restrict__ w2,
                              const float* __restrict__ w3, const float* __restrict__ w4,
                              short* __restrict__ out)
{
    const int E0 = 1179648, E1 = E0 + 262144, E2 = E1 + 589824, E3 = E2 + 409600;
    for (int i = blockIdx.x * blockDim.x + threadIdx.x; i < E3; i += gridDim.x * blockDim.x) {
        const float* w; int OC, CI, KS, j;
        if (i < E0)      { w = w1; OC = 512; CI = 256; KS = 3; j = i; }
        else if (i < E1) { w = w2; OC = 512; CI = 512; KS = 1; j = i - E0; }
        else if (i < E2) { w = w3; OC = 128; CI = 512; KS = 3; j = i - E1; }
        else             { w = w4; OC = 128; CI = 128; KS = 5; j = i - E2; }
        const int ic = j % CI;
        int t = j / CI;
        const int oc = t % OC;
        const int s = t / OC;
        const int ky = s / KS, kx = s % KS;
        out[i] = (short)f2bf(w[(((size_t)oc * CI + ic) * KS + ky) * KS + kx]);
    }
}

__global__ void pack_w1_f32(const float* __restrict__ w, float* __restrict__ out)
{
    const int total = 128 * 128 * 25;
    for (int i = blockIdx.x * blockDim.x + threadIdx.x; i < total; i += gridDim.x * blockDim.x) {
        const int oc = i % 128;
        int t = i / 128;
        const int ic = t % 128;
        const int s = t / 128;
        const int ky = s / 5, kx = s % 5;
        out[i] = w[(((size_t)oc * 128 + ic) * 5 + ky) * 5 + kx];
    }
}

// feature transposes -> bf16 channel-last, concatenated
__global__ void transpose_all(const float* __restrict__ f0, const float* __restrict__ f1,
                              const float* __restrict__ f2, const float* __restrict__ f3,
                              short* __restrict__ out)
{
    const int O1 = 2230272, O2 = O1 + 557568, O3 = O2 + 139392, O4 = O3 + 34848;
    for (int i = blockIdx.x * blockDim.x + threadIdx.x; i < O4; i += gridDim.x * blockDim.x) {
        const float* f; int Hl, Wl, j;
        if (i < O1)      { f = f0; Hl = 32; Wl = 88; j = i; }
        else if (i < O2) { f = f1; Hl = 16; Wl = 44; j = i - O1; }
        else if (i < O3) { f = f2; Hl = 8;  Wl = 22; j = i - O2; }
        else             { f = f3; Hl = 4;  Wl = 11; j = i - O3; }
        const int c = j % 132;
        int t = j / 132;
        const int x = t % Wl; t /= Wl;
        const int y = t % Hl; t /= Hl;
        const int n = t;
        out[i] = (short)f2bf(f[(((size_t)n * 132 + c) * Hl + y) * Wl + x]);
    }
}

// offsw + projection compaction fused (unchanged)
__global__ __launch_bounds__(64)
void offsw_proj(const float* __restrict__ qn, const float* __restrict__ bev_pos,
                const float* __restrict__ off_w, const float* __restrict__ off_b,
                const float* __restrict__ sw_w, const float* __restrict__ sw_b,
                const float* __restrict__ l2i,
                float* __restrict__ refp, float* __restrict__ swts,
                float2* __restrict__ recs, int* __restrict__ recn, int* __restrict__ cnts)
{
    const int pix = blockIdx.x;
    const int tid = threadIdx.x;
    __shared__ float qv[128];
    __shared__ float swraw[32];
    __shared__ float rp[24];
    qv[tid]      = qn[(size_t)tid * HW + pix];
    qv[tid + 64] = qn[(size_t)(tid + 64) * HW + pix];
    __syncthreads();

    if (tid < 24) {
        float acc = off_b[tid];
        for (int c = 0; c < 128; ++c) acc = fmaf(qv[c], off_w[tid * 128 + c], acc);
        const float s = 1.0f / (1.0f + expf(-acc));
        const int coord = tid % 3;
        const float rng = (coord < 2) ? 0.250001f : 4.000001f;
        const float v = s * rng * 2.0f - rng;
        const float lo[3]   = {-50.f, -50.f, -5.f};
        const float span[3] = {100.f, 100.f, 8.f};
        const float rv = bev_pos[pix * 3 + coord] * span[coord] + lo[coord] + v;
        refp[pix * 24 + tid] = rv;
        rp[tid] = rv;
    } else if (tid >= 32) {
        const int j = tid - 32;
        float acc = sw_b[j];
        for (int c = 0; c < 128; ++c) acc = fmaf(qv[c], sw_w[j * 128 + c], acc);
        swraw[j] = acc;
    }
    __syncthreads();
    if (tid < 8) {
        float m = -1e30f;
#pragma unroll
        for (int l = 0; l < 4; ++l) m = fmaxf(m, swraw[tid * 4 + l]);
        float e[4], sum = 0.f;
#pragma unroll
        for (int l = 0; l < 4; ++l) { e[l] = expf(swraw[tid * 4 + l] - m); sum += e[l]; }
        const float inv = 1.0f / sum;
#pragma unroll
        for (int l = 0; l < 4; ++l) swts[pix * 32 + tid * 4 + l] = e[l] * inv;
    }

    bool keep = false;
    float gx = -2.f, gy = -2.f;
    int p = 0, n = 0;
    if (tid < 48) {
        p = tid / 6;
        n = tid - p * 6;
        const float X = rp[p * 3 + 0], Y = rp[p * 3 + 1], Z = rp[p * 3 + 2];
        const float* m = l2i + n * 16;
        const float cx = m[0] * X + m[1] * Y + m[2]  * Z + m[3];
        const float cy = m[4] * X + m[5] * Y + m[6]  * Z + m[7];
        const float cz = m[8] * X + m[9] * Y + m[10] * Z + m[11];
        const bool valid = cz > 1e-5f;
        const float zz = fmaxf(cz, 1e-5f);
        gx = valid ? (cx / zz) * (2.0f / 704.0f) - 1.0f : -2.0f;
        gy = valid ? (cy / zz) * (2.0f / 256.0f) - 1.0f : -2.0f;
        keep = (gx > -1.092f) && (gx < 1.092f) && (gy > -1.26f) && (gy < 1.26f);
    }
    const unsigned long long bm = __ballot(keep);
    if (keep) {
        const unsigned long long gmask = 0x3Full << (p * 6);
        const int slot = __popcll(bm & ((1ull << tid) - 1ull) & gmask);
        recs[(size_t)pix * 48 + p * 6 + slot] = make_float2(gx, gy);
        recn[(size_t)pix * 48 + p * 6 + slot] = n;
    }
    if (tid < 48 && (tid % 6) == 0) {
        const unsigned long long gmask = 0x3Full << (p * 6);
        cnts[pix * 8 + p] = __popcll(bm & gmask);
    }
}

// ---------------------------------------------------------------------------
// sampling over compacted records; bf16 taps; 4 independent tap accumulators.
// ---------------------------------------------------------------------------
__global__ __launch_bounds__(128)
void sample_k2(const float* __restrict__ refp, const float* __restrict__ swts,
               const float2* __restrict__ recs, const int* __restrict__ recn,
               const int* __restrict__ cnts,
               const short* __restrict__ fT0, const short* __restrict__ fT1,
               const short* __restrict__ fT2, const short* __restrict__ fT3,
               short* __restrict__ sfo)
{
    const int pix = blockIdx.x;
    const int tid = threadIdx.x;                   // 128
    __shared__ float rp[24], sw[32], tail[32];
    __shared__ float2 rec[48];
    __shared__ int rn[48];
    __shared__ int cnt[8];
    if (tid < 24) rp[tid] = refp[pix * 24 + tid];
    if (tid < 32) sw[tid] = swts[pix * 32 + tid];
    if (tid < 48) { rec[tid] = recs[(size_t)pix * 48 + tid]; rn[tid] = recn[(size_t)pix * 48 + tid]; }
    if (tid < 8)  cnt[tid] = cnts[pix * 8 + tid];
    __syncthreads();

    const short* fT[4] = {fT0, fT1, fT2, fT3};
    const int HL[4] = {32, 16, 8, 4};
    const int WL[4] = {88, 44, 22, 11};

    float acc[8], accT[8];
#pragma unroll
    for (int p = 0; p < 8; ++p) {
        float a0 = 0.f, a1 = 0.f, a2 = 0.f, a3 = 0.f;
        float b0 = 0.f, b1 = 0.f, b2 = 0.f, b3 = 0.f;
        const int c = cnt[p];
        for (int r = 0; r < c; ++r) {
            const float gx = rec[p * 6 + r].x;
            const float gy = rec[p * 6 + r].y;
            const int n = rn[p * 6 + r];
#pragma unroll
            for (int l = 0; l < 4; ++l) {
                const float wl = sw[p * 4 + l];
                const int Hl = HL[l], Wl = WL[l];
                const float fx = (gx + 1.0f) * 0.5f * (float)Wl - 0.5f;
                const float fy = (gy + 1.0f) * 0.5f * (float)Hl - 0.5f;
                if (!(fx >= -1.0f && fx < (float)Wl && fy >= -1.0f && fy < (float)Hl))
                    continue;
                const float x0f = floorf(fx), y0f = floorf(fy);
                const int x0 = (int)x0f, y0 = (int)y0f;
                const int x1 = x0 + 1, y1 = y0 + 1;
                const float wx1 = fx - x0f, wy1 = fy - y0f;
                const float wx0 = 1.0f - wx1, wy0 = 1.0f - wy1;
                const bool okx0 = (x0 >= 0), okx1 = (x1 < Wl);
                const bool oky0 = (y0 >= 0), oky1 = (y1 < Hl);
                const short* fb = fT[l] + (size_t)n * Hl * Wl * 132;
                if (okx0 && oky0) {
                    const float wt = wx0 * wy0 * wl;
                    const short* tp = fb + (size_t)(y0 * Wl + x0) * 132;
                    a0 = fmaf(bf2f(tp[tid]), wt, a0);
                    if (tid < 4) b0 = fmaf(bf2f(tp[128 + tid]), wt, b0);
                }
                if (okx1 && oky0) {
                    const float wt = wx1 * wy0 * wl;
                    const short* tp = fb + (size_t)(y0 * Wl + x1) * 132;
                    a1 = fmaf(bf2f(tp[tid]), wt, a1);
                    if (tid < 4) b1 = fmaf(bf2f(tp[128 + tid]), wt, b1);
                }
                if (okx0 && oky1) {
                    const float wt = wx0 * wy1 * wl;
                    const short* tp = fb + (size_t)(y1 * Wl + x0) * 132;
                    a2 = fmaf(bf2f(tp[tid]), wt, a2);
                    if (tid < 4) b2 = fmaf(bf2f(tp[128 + tid]), wt, b2);
                }
                if (okx1 && oky1) {
                    const float wt = wx1 * wy1 * wl;
                    const short* tp = fb + (size_t)(y1 * Wl + x1) * 132;
                    a3 = fmaf(bf2f(tp[tid]), wt, a3);
                    if (tid < 4) b3 = fmaf(bf2f(tp[128 + tid]), wt, b3);
                }
            }
        }
        acc[p]  = (a0 + a1) + (a2 + a3);
        accT[p] = (b0 + b1) + (b2 + b3);
    }

    if (tid < 4) {
#pragma unroll
        for (int p = 0; p < 8; ++p) tail[p * 4 + tid] = accT[p];
    }
    __syncthreads();

    float sf1 = 0.f, sf2 = 0.f;
#pragma unroll
    for (int p = 0; p < 8; ++p) {
        const float dx = rp[p * 3]     - tail[p * 4 + 0];
        const float dy = rp[p * 3 + 1] - tail[p * 4 + 1];
        const float dz = rp[p * 3 + 2] - tail[p * 4 + 2];
        const float wgt = expf(-0.1f * (dx * dx + dy * dy + dz * dz));
        sf1 += acc[p];
        sf2 += acc[p] * wgt;
    }
    const int y = pix / WID, x = pix % WID;
    const size_t po = ((size_t)(y + 1) * 102 + (x + 1)) * 256;
    sfo[po + tid]       = (short)f2bf(sf1);
    sfo[po + 128 + tid] = (short)f2bf(sf2);
}

// ---------------------------------------------------------------------------

extern "C" void kernel_launch(void* const* d_in, const int* in_sizes, int n_in,
                              void* d_out, int out_size, void* d_ws, size_t ws_size,
                              hipStream_t stream)
{
    const float* bev_query = (const float*)d_in[0];
    const float* bev_pos   = (const float*)d_in[1];
    const float* l2i       = (const float*)d_in[2];
    const float* feat0     = (const float*)d_in[3];
    const float* feat1     = (const float*)d_in[4];
    const float* feat2     = (const float*)d_in[5];
    const float* feat3     = (const float*)d_in[6];
    const float* in_w      = (const float*)d_in[7];
    const float* in_b      = (const float*)d_in[8];
    const float* off_w     = (const float*)d_in[9];
    const float* off_b     = (const float*)d_in[10];
    const float* sw_w      = (const float*)d_in[11];
    const float* sw_b      = (const float*)d_in[12];
    const float* mid_w1    = (const float*)d_in[13];
    const float* mid_b1    = (const float*)d_in[14];
    const float* mid_w2    = (const float*)d_in[15];
    const float* mid_b2    = (const float*)d_in[16];
    const float* mid_w3    = (const float*)d_in[17];
    const float* mid_b3    = (const float*)d_in[18];
    const float* out_w     = (const float*)d_in[19];
    const float* out_b     = (const float*)d_in[20];
    float* out = (float*)d_out;

    // ---- workspace layout (lifetime-aliased) ----
    float* ws    = (float*)d_ws;
    float* qn    = ws;                       // 1,280,000
    float* refp  = qn + 1280000;             //   240,000
    float* swts  = refp + 240000;            //   320,000
    float* E     = swts + 320000;            // 6,400,000 (slab5 | fTb+recs | m1_cl | slab3)
    float* F     = E + 6400000;              // 1,800,000 (xpadP+wpk1f | sf_cl | q2pad)
    float* H     = F + 1800000;              // 2,700,000 (m2_cl)
    short* wp_all= (short*)(H + 2700000);    // 2,441,216 sh

    float*  slab  = E;                       // conv1: 5 slabs; later convs: 3 slabs
    short*  fT0   = (short*)E;               // 2,962,080 shorts (bf16 feats)
    short*  fT1   = fT0 + 2230272;
    short*  fT2   = fT1 + 557568;
    short*  fT3   = fT2 + 139392;
    float2* recs  = (float2*)(E + 1600000);  // 480,000 f2
    int*    recn  = (int*)(E + 2560000);     // 480,000
    int*    cnts  = (int*)(E + 3040000);     //  80,000
    short*  m1_cl = (short*)E;               // 5,120,000 sh [100][100][512]
    float*  xpadP = F;                       // 1,384,448 f
    float*  wpk1f = F + 1384448;             //   409,600 f
    short*  sf_cl = (short*)F;               // 2,663,424 sh [102][102][256]
    short*  q2pad = (short*)F;               // 1,384,448 sh [104][104][128]
    short*  m2_cl = (short*)H;               // 5,326,848 sh [102][102][512]
    short*  wp_m1 = wp_all;                  // 1,179,648
    short*  wp_m2 = wp_m1 + 1179648;         //   262,144
    short*  wp_m3 = wp_m2 + 262144;          //   589,824
    short*  wp_out= wp_m3 + 589824;          //   409,600

    const dim3 blk(256);

    // ---- weight packing ----
    hipLaunchKernelGGL(pack_w1_f32, dim3(1600), blk, 0, stream, in_w, wpk1f);
    hipLaunchKernelGGL(pack_all_bf16, dim3(9536), blk, 0, stream,
                       mid_w1, mid_w2, mid_w3, out_w, wp_all);

    // ---- 1. q1 slabs = conv5x5_f32(bev_query), then qn = inorm(q1) fused ----
    hipLaunchKernelGGL(pad_xpad, dim3(5408), blk, 0, stream, bev_query, xpadP);
    hipLaunchKernelGGL(conv1_f32, dim3(4, 50, 5), dim3(128), 0, stream, wpk1f, xpadP, slab);
    hipLaunchKernelGGL(red_norm_k<5>, dim3(128), blk, 0, stream, in_b, bev_query, slab, qn);

    // ---- 2. ref points + softmax weights + projection compaction ----
    hipLaunchKernelGGL(offsw_proj, dim3(HW), dim3(64), 0, stream,
                       qn, bev_pos, off_w, off_b, sw_w, sw_b, l2i,
                       refp, swts, recs, recn, cnts);

    // ---- 3. feature transposes -> bf16 (slab5 dead) ----
    hipLaunchKernelGGL(transpose_all, dim3(11571), blk, 0, stream,
                       feat0, feat1, feat2, feat3, fT0);

    // ---- 4. sampling -> sf_cl bf16 padded(1) ----
    hipMemsetAsync(sf_cl, 0, (size_t)2663424 * 2, stream);
    hipLaunchKernelGGL(sample_k2, dim3(HW), dim3(128), 0, stream,
                       refp, swts, recs, recn, cnts, fT0, fT1, fT2, fT3, sf_cl);

    // ---- 5. m1 = gelu(conv3x3 256->512) ----
    hipLaunchKernelGGL((mfma_conv<256, 3, 512, 1, true, 0, 100, 1>), dim3(4, 25, 4), blk, 0, stream,
                       wp_m1, sf_cl, mid_b1, nullptr, m1_cl);
    // ---- 6. m2 = gelu(conv1x1 512->512) -> padded(1) ----
    hipMemsetAsync(m2_cl, 0, (size_t)5326848 * 2, stream);
    hipLaunchKernelGGL((mfma_conv<512, 1, 512, 1, true, 1, 102, 1>), dim3(4, 25, 4), blk, 0, stream,
                       wp_m2, m1_cl, mid_b2, nullptr, m2_cl);
    // ---- 7. q2 = inorm(qn + conv3x3 512->128) ----
    hipLaunchKernelGGL((mfma_conv<512, 3, 128, 2, false, 0, 0, 3>), dim3(1, 25, 12), blk, 0, stream,
                       wp_m3, m2_cl, mid_b3, slab, nullptr);
    hipLaunchKernelGGL(red_norm_k<3>, dim3(128), blk, 0, stream, mid_b3, qn, slab, qn);
    // ---- 8. q3 = inorm(qn + conv5x5 bf16) ----
    hipLaunchKernelGGL((pad_cl_cast<128, 2>), dim3(5411), blk, 0, stream, qn, q2pad);
    hipLaunchKernelGGL((mfma_conv<128, 5, 128, 2, false, 0, 0, 3>), dim3(1, 25, 12), blk, 0, stream,
                       wp_out, q2pad, out_b, slab, nullptr);
    hipLaunchKernelGGL(red_norm_k<3>, dim3(128), blk, 0, stream, out_b, qn, slab, out);
}

// Round 9
// 817.506 us; speedup vs baseline: 1.0569x; 1.0569x over previous
//
#include <hip/hip_runtime.h>
#include <cstddef>

// ---------------------------------------------------------------------------
// SegTransformerDecoder — round 9 (round 8 + Bs index fix: +256 -> +64).
//  * conv1_f32 v4: 256-thr / 128x128-tile / 500-block, conflict-free Bs reads.
// ---------------------------------------------------------------------------

#define HW   10000
#define WID  100

typedef __attribute__((ext_vector_type(8))) __bf16 bf16x8;
typedef __attribute__((ext_vector_type(4))) float f32x4;
typedef __attribute__((ext_vector_type(4))) unsigned int uint4v;

__device__ __forceinline__ float gelu_exact(float x) {
    return 0.5f * x * (1.0f + erff(x * 0.7071067811865475f));
}
__device__ __forceinline__ unsigned short f2bf(float v) {
    unsigned int b = __float_as_uint(v);
    return (unsigned short)((b + 0x7FFFu + ((b >> 16) & 1u)) >> 16);
}
__device__ __forceinline__ float bf2f(short s) {
    return __uint_as_float(((unsigned int)(unsigned short)s) << 16);
}
__device__ __forceinline__ bf16x8 load_frag(const short* p) {
    return __builtin_bit_cast(bf16x8, *(const uint4v*)p);
}

// ---------------------------------------------------------------------------
// conv1_f32 v4 (decision chain, exact fp32).
// input xpadP: channel-major padded(2) [128][104][104] fp32
// weights wpkf: [ky][kx][ic][oc] fp32
// block 256 thr, tile 128oc x 128pix (4 rows x 32 cols);
// thread = 8oc (og=t>>4) x 8pix split as {pg*4..+3, 64+pg*4..+3} (pg=t&15).
// grid (4, 25, 5); z = ky; slab[z][oc][pix] store.
// ---------------------------------------------------------------------------
__global__ __launch_bounds__(256)
void conv1_f32(const float* __restrict__ wpkf, const float* __restrict__ xpadP,
               float* __restrict__ slab)
{
    __shared__ float As[2048];      // [ic 16][oc 128]
    __shared__ float Bs[2048];      // [ic 16][pix 128]
    const int t  = threadIdx.x;
    const int og = t >> 4;          // 16 groups of 8 oc
    const int pg = t & 15;          // 16 pix groups
    const int x0 = blockIdx.x * 32, y0 = blockIdx.y * 4;
    const int ky = blockIdx.z;

    // staging (contiguous, conflict-free): element e -> ic = e>>7, p = e&127
    const int e0 = t * 4, e1 = 1024 + t * 4;
    const int ica = e0 >> 7, pa = e0 & 127;
    const int icb = e1 >> 7, pb = e1 & 127;
    const int rowa = (y0 + (pa >> 5) + ky) * 104 + x0 + (pa & 31);
    const int rowb = (y0 + (pb >> 5) + ky) * 104 + x0 + (pb & 31);

    float acc[8][8];
#pragma unroll
    for (int i = 0; i < 8; ++i)
#pragma unroll
        for (int j = 0; j < 8; ++j) acc[i][j] = 0.f;

    for (int kx = 0; kx < 5; ++kx) {
        for (int ic0 = 0; ic0 < 128; ic0 += 16) {
            __syncthreads();
            const float* asrc = wpkf + (size_t)((ky * 5 + kx) * 128 + ic0) * 128;
            *(float4*)(As + e0) = *(const float4*)(asrc + e0);
            *(float4*)(As + e1) = *(const float4*)(asrc + e1);
            float4 bva, bvb;
            __builtin_memcpy(&bva, xpadP + (size_t)(ic0 + ica) * 10816 + rowa + kx, 16);
            __builtin_memcpy(&bvb, xpadP + (size_t)(ic0 + icb) * 10816 + rowb + kx, 16);
            *(float4*)(Bs + e0) = bva;
            *(float4*)(Bs + e1) = bvb;
            __syncthreads();
#pragma unroll
            for (int k = 0; k < 16; ++k) {
                float a[8], b[8];
                *(float4*)(a)     = *(float4*)(As + k * 128 + og * 8);
                *(float4*)(a + 4) = *(float4*)(As + k * 128 + og * 8 + 4);
                *(float4*)(b)     = *(float4*)(Bs + k * 128 + pg * 4);       // pix pg*4..+3
                *(float4*)(b + 4) = *(float4*)(Bs + k * 128 + 64 + pg * 4);  // pix 64+pg*4..+3
#pragma unroll
                for (int i = 0; i < 8; ++i)
#pragma unroll
                    for (int j = 0; j < 8; ++j)
                        acc[i][j] = fmaf(a[i], b[j], acc[i][j]);
            }
        }
    }

    // epilogue: two 4-pixel runs per thread, float4 stores
    float* sl = slab + (size_t)ky * 1280000;
#pragma unroll
    for (int h = 0; h < 2; ++h) {
        const int p  = h * 64 + pg * 4;
        const int py = y0 + (p >> 5);
        const int px = x0 + (p & 31);
        if (px >= 100) continue;
#pragma unroll
        for (int i = 0; i < 8; ++i) {
            float* dst = sl + (size_t)(og * 8 + i) * HW + py * WID + px;
            __builtin_memcpy(dst, &acc[i][h * 4], 16);
        }
    }
}

// ---------------------------------------------------------------------------
// bf16 MFMA implicit-GEMM conv, 128oc x 128pix block tile (unchanged).
// ---------------------------------------------------------------------------
template<int CIN, int KS, int COUT, int EPI, bool ACT, int OPAD, int OPW, int KSPLIT>
__global__ __launch_bounds__(256)
void mfma_conv(const short* __restrict__ wpk, const short* __restrict__ xcl,
               const float* __restrict__ bias,
               float* __restrict__ outcm, short* __restrict__ outcl)
{
    constexpr int PW = 100 + 2 * (KS / 2);
    constexpr int CHUNK = (KS + KSPLIT - 1) / KSPLIT;
    const int lane = threadIdx.x & 63;
    const int wave = threadIdx.x >> 6;
    const int wr = wave >> 1;
    const int wc = wave & 1;
    const int lq = lane >> 4;
    const int ln = lane & 15;

    const int oc0 = blockIdx.x * 128;
    const int y0  = blockIdx.y * 4;
    const int zb  = blockIdx.z;
    const int bx  = (KSPLIT > 1) ? (zb & 3) : zb;
    const int ks  = (KSPLIT > 1) ? (zb >> 2) : 0;
    const int x0  = bx * 32;
    const int ky_lo = ks * CHUNK;
    const int ky_hi = (ky_lo + CHUNK < KS) ? ky_lo + CHUNK : KS;

    int bpix[4];
#pragma unroll
    for (int nt = 0; nt < 4; ++nt) {
        const int nl = wc * 64 + nt * 16 + ln;
        bpix[nt] = (y0 + (nl >> 5)) * PW + (x0 + (nl & 31));
    }

    f32x4 acc[4][4];
#pragma unroll
    for (int mt = 0; mt < 4; ++mt)
#pragma unroll
        for (int nt = 0; nt < 4; ++nt)
#pragma unroll
            for (int r = 0; r < 4; ++r) acc[mt][nt][r] = 0.f;

    const int arow0 = oc0 + wr * 64 + ln;

    for (int ky = ky_lo; ky < ky_hi; ++ky) {
#pragma unroll
        for (int kx = 0; kx < KS; ++kx) {
            const short* wsl = wpk + (size_t)((ky * KS + kx) * COUT) * CIN;
            const short* xsl = xcl + (size_t)(ky * PW + kx) * CIN;
            for (int ic0 = 0; ic0 < CIN; ic0 += 32) {
                bf16x8 a[4], b[4];
#pragma unroll
                for (int mt = 0; mt < 4; ++mt)
                    a[mt] = load_frag(wsl + (size_t)(arow0 + mt * 16) * CIN + ic0 + lq * 8);
#pragma unroll
                for (int nt = 0; nt < 4; ++nt)
                    b[nt] = load_frag(xsl + (size_t)bpix[nt] * CIN + ic0 + lq * 8);
#pragma unroll
                for (int mt = 0; mt < 4; ++mt)
#pragma unroll
                    for (int nt = 0; nt < 4; ++nt)
                        acc[mt][nt] = __builtin_amdgcn_mfma_f32_16x16x32_bf16(
                            a[mt], b[nt], acc[mt][nt], 0, 0, 0);
            }
        }
    }

#pragma unroll
    for (int mt = 0; mt < 4; ++mt) {
        const int ocr = oc0 + wr * 64 + mt * 16 + lq * 4;
        float bb[4];
        if (EPI == 1) {
            const float4 bv = *(const float4*)(bias + ocr);
            bb[0] = bv.x; bb[1] = bv.y; bb[2] = bv.z; bb[3] = bv.w;
        }
#pragma unroll
        for (int nt = 0; nt < 4; ++nt) {
            const int nl = wc * 64 + nt * 16 + ln;
            const int x = x0 + (nl & 31);
            const int y = y0 + (nl >> 5);
            if (x >= 100) continue;
            if (EPI == 1) {
                float v[4];
#pragma unroll
                for (int r = 0; r < 4; ++r) {
                    float t = acc[mt][nt][r] + bb[r];
                    if (ACT) t = gelu_exact(t);
                    v[r] = t;
                }
                ushort4 pk;
                pk.x = f2bf(v[0]); pk.y = f2bf(v[1]); pk.z = f2bf(v[2]); pk.w = f2bf(v[3]);
                *(ushort4*)(outcl + ((size_t)(y + OPAD) * OPW + (x + OPAD)) * COUT + ocr) = pk;
            } else {
                const int pix = y * WID + x;
#pragma unroll
                for (int r = 0; r < 4; ++r)
                    outcm[((size_t)ks * COUT + ocr + r) * HW + pix] = acc[mt][nt][r];
            }
        }
    }
}

// fused: out = inorm(bias + res + sum_z slab[z])
template<int NS>
__global__ __launch_bounds__(256)
void red_norm_k(const float* __restrict__ bias, const float* __restrict__ res,
                const float* __restrict__ slab, float* __restrict__ outp)
{
    const int c = blockIdx.x, tid = threadIdx.x;
    const size_t base = (size_t)c * HW;
    const float bc = bias[c];
    float v[40];
    float s1 = 0.f, s2 = 0.f;
#pragma unroll
    for (int k = 0; k < 40; ++k) {
        const int i = tid + k * 256;
        float x = 0.f;
        if (i < HW) {
            x = bc + res[base + i];
#pragma unroll
            for (int z = 0; z < NS; ++z) x += slab[(size_t)z * 1280000 + base + i];
            s1 += x; s2 += x * x;
        }
        v[k] = x;
    }
    __shared__ float r1[256], r2[256];
    r1[tid] = s1; r2[tid] = s2; __syncthreads();
    for (int o = 128; o > 0; o >>= 1) {
        if (tid < o) { r1[tid] += r1[tid + o]; r2[tid] += r2[tid + o]; }
        __syncthreads();
    }
    const float mean = r1[0] * 1e-4f;
    const float var  = fmaxf(r2[0] * 1e-4f - mean * mean, 0.f);
    const float rstd = rsqrtf(var + 1e-5f);
#pragma unroll
    for (int k = 0; k < 40; ++k) {
        const int i = tid + k * 256;
        if (i < HW) outp[base + i] = (v[k] - mean) * rstd;
    }
}

// fp32 channel-major [128][100][100] -> channel-major padded(2) [128][104][104]
__global__ void pad_xpad(const float* __restrict__ in, float* __restrict__ out)
{
    const int total = 128 * 104 * 104;
    for (int i = blockIdx.x * blockDim.x + threadIdx.x; i < total; i += gridDim.x * blockDim.x) {
        const int c = i / 10816;
        const int r = i % 10816;
        const int y = r / 104 - 2;
        const int x = r % 104 - 2;
        float v = 0.f;
        if (x >= 0 && x < 100 && y >= 0 && y < 100) v = in[(size_t)c * HW + y * WID + x];
        out[i] = v;
    }
}

template<int C, int PAD>
__global__ void pad_cl_cast(const float* __restrict__ in, short* __restrict__ out)
{
    constexpr int PW = 100 + 2 * PAD;
    const int total = PW * PW * C;
    for (int i = blockIdx.x * blockDim.x + threadIdx.x; i < total; i += gridDim.x * blockDim.x) {
        const int c = i % C;
        const int p = i / C;
        const int x = p % PW - PAD;
        const int y = p / PW - PAD;
        float v = 0.f;
        if (x >= 0 && x < 100 && y >= 0 && y < 100) v = in[(size_t)c * HW + y * WID + x];
        out[i] = (short)f2bf(v);
    }
}

__global__ void pack_all_bf16(const float* __restrict__ w1, const float* __restrict__ w2,
                              const float* __restrict__ w3, const float* __restrict__ w4,
                              short* __restrict__ out)
{
    const int E0 = 1179648, E1 = E0 + 262144, E2 = E1 + 589824, E3 = E2 + 409600;
    for (int i = blockIdx.x * blockDim.x + threadIdx.x; i < E3; i += gridDim.x * blockDim.x) {
        const float* w; int OC, CI, KS, j;
        if (i < E0)      { w = w1; OC = 512; CI = 256; KS = 3; j = i; }
        else if (i < E1) { w = w2; OC = 512; CI = 512; KS = 1; j = i - E0; }
        else if (i < E2) { w = w3; OC = 128; CI = 512; KS = 3; j = i - E1; }
        else             { w = w4; OC = 128; CI = 128; KS = 5; j = i - E2; }
        const int ic = j % CI;
        int t = j / CI;
        const int oc = t % OC;
        const int s = t / OC;
        const int ky = s / KS, kx = s % KS;
        out[i] = (short)f2bf(w[(((size_t)oc * CI + ic) * KS + ky) * KS + kx]);
    }
}

__global__ void pack_w1_f32(const float* __restrict__ w, float* __restrict__ out)
{
    const int total = 128 * 128 * 25;
    for (int i = blockIdx.x * blockDim.x + threadIdx.x; i < total; i += gridDim.x * blockDim.x) {
        const int oc = i % 128;
        int t = i / 128;
        const int ic = t % 128;
        const int s = t / 128;
        const int ky = s / 5, kx = s % 5;
        out[i] = w[(((size_t)oc * 128 + ic) * 5 + ky) * 5 + kx];
    }
}

// feature transposes -> bf16 channel-last, concatenated
__global__ void transpose_all(const float* __restrict__ f0, const float* __restrict__ f1,
                              const float* __restrict__ f2, const float* __restrict__ f3,
                              short* __restrict__ out)
{
    const int O1 = 2230272, O2 = O1 + 557568, O3 = O2 + 139392, O4 = O3 + 34848;
    for (int i = blockIdx.x * blockDim.x + threadIdx.x; i < O4; i += gridDim.x * blockDim.x) {
        const float* f; int Hl, Wl, j;
        if (i < O1)      { f = f0; Hl = 32; Wl = 88; j = i; }
        else if (i < O2) { f = f1; Hl = 16; Wl = 44; j = i - O1; }
        else if (i < O3) { f = f2; Hl = 8;  Wl = 22; j = i - O2; }
        else             { f = f3; Hl = 4;  Wl = 11; j = i - O3; }
        const int c = j % 132;
        int t = j / 132;
        const int x = t % Wl; t /= Wl;
        const int y = t % Hl; t /= Hl;
        const int n = t;
        out[i] = (short)f2bf(f[(((size_t)n * 132 + c) * Hl + y) * Wl + x]);
    }
}

// offsw + projection compaction fused (unchanged)
__global__ __launch_bounds__(64)
void offsw_proj(const float* __restrict__ qn, const float* __restrict__ bev_pos,
                const float* __restrict__ off_w, const float* __restrict__ off_b,
                const float* __restrict__ sw_w, const float* __restrict__ sw_b,
                const float* __restrict__ l2i,
                float* __restrict__ refp, float* __restrict__ swts,
                float2* __restrict__ recs, int* __restrict__ recn, int* __restrict__ cnts)
{
    const int pix = blockIdx.x;
    const int tid = threadIdx.x;
    __shared__ float qv[128];
    __shared__ float swraw[32];
    __shared__ float rp[24];
    qv[tid]      = qn[(size_t)tid * HW + pix];
    qv[tid + 64] = qn[(size_t)(tid + 64) * HW + pix];
    __syncthreads();

    if (tid < 24) {
        float acc = off_b[tid];
        for (int c = 0; c < 128; ++c) acc = fmaf(qv[c], off_w[tid * 128 + c], acc);
        const float s = 1.0f / (1.0f + expf(-acc));
        const int coord = tid % 3;
        const float rng = (coord < 2) ? 0.250001f : 4.000001f;
        const float v = s * rng * 2.0f - rng;
        const float lo[3]   = {-50.f, -50.f, -5.f};
        const float span[3] = {100.f, 100.f, 8.f};
        const float rv = bev_pos[pix * 3 + coord] * span[coord] + lo[coord] + v;
        refp[pix * 24 + tid] = rv;
        rp[tid] = rv;
    } else if (tid >= 32) {
        const int j = tid - 32;
        float acc = sw_b[j];
        for (int c = 0; c < 128; ++c) acc = fmaf(qv[c], sw_w[j * 128 + c], acc);
        swraw[j] = acc;
    }
    __syncthreads();
    if (tid < 8) {
        float m = -1e30f;
#pragma unroll
        for (int l = 0; l < 4; ++l) m = fmaxf(m, swraw[tid * 4 + l]);
        float e[4], sum = 0.f;
#pragma unroll
        for (int l = 0; l < 4; ++l) { e[l] = expf(swraw[tid * 4 + l] - m); sum += e[l]; }
        const float inv = 1.0f / sum;
#pragma unroll
        for (int l = 0; l < 4; ++l) swts[pix * 32 + tid * 4 + l] = e[l] * inv;
    }

    bool keep = false;
    float gx = -2.f, gy = -2.f;
    int p = 0, n = 0;
    if (tid < 48) {
        p = tid / 6;
        n = tid - p * 6;
        const float X = rp[p * 3 + 0], Y = rp[p * 3 + 1], Z = rp[p * 3 + 2];
        const float* m = l2i + n * 16;
        const float cx = m[0] * X + m[1] * Y + m[2]  * Z + m[3];
        const float cy = m[4] * X + m[5] * Y + m[6]  * Z + m[7];
        const float cz = m[8] * X + m[9] * Y + m[10] * Z + m[11];
        const bool valid = cz > 1e-5f;
        const float zz = fmaxf(cz, 1e-5f);
        gx = valid ? (cx / zz) * (2.0f / 704.0f) - 1.0f : -2.0f;
        gy = valid ? (cy / zz) * (2.0f / 256.0f) - 1.0f : -2.0f;
        keep = (gx > -1.092f) && (gx < 1.092f) && (gy > -1.26f) && (gy < 1.26f);
    }
    const unsigned long long bm = __ballot(keep);
    if (keep) {
        const unsigned long long gmask = 0x3Full << (p * 6);
        const int slot = __popcll(bm & ((1ull << tid) - 1ull) & gmask);
        recs[(size_t)pix * 48 + p * 6 + slot] = make_float2(gx, gy);
        recn[(size_t)pix * 48 + p * 6 + slot] = n;
    }
    if (tid < 48 && (tid % 6) == 0) {
        const unsigned long long gmask = 0x3Full << (p * 6);
        cnts[pix * 8 + p] = __popcll(bm & gmask);
    }
}

// ---------------------------------------------------------------------------
// sampling over compacted records; bf16 taps; 4 independent tap accumulators.
// ---------------------------------------------------------------------------
__global__ __launch_bounds__(128)
void sample_k2(const float* __restrict__ refp, const float* __restrict__ swts,
               const float2* __restrict__ recs, const int* __restrict__ recn,
               const int* __restrict__ cnts,
               const short* __restrict__ fT0, const short* __restrict__ fT1,
               const short* __restrict__ fT2, const short* __restrict__ fT3,
               short* __restrict__ sfo)
{
    const int pix = blockIdx.x;
    const int tid = threadIdx.x;                   // 128
    __shared__ float rp[24], sw[32], tail[32];
    __shared__ float2 rec[48];
    __shared__ int rn[48];
    __shared__ int cnt[8];
    if (tid < 24) rp[tid] = refp[pix * 24 + tid];
    if (tid < 32) sw[tid] = swts[pix * 32 + tid];
    if (tid < 48) { rec[tid] = recs[(size_t)pix * 48 + tid]; rn[tid] = recn[(size_t)pix * 48 + tid]; }
    if (tid < 8)  cnt[tid] = cnts[pix * 8 + tid];
    __syncthreads();

    const short* fT[4] = {fT0, fT1, fT2, fT3};
    const int HL[4] = {32, 16, 8, 4};
    const int WL[4] = {88, 44, 22, 11};

    float acc[8], accT[8];
#pragma unroll
    for (int p = 0; p < 8; ++p) {
        float a0 = 0.f, a1 = 0.f, a2 = 0.f, a3 = 0.f;
        float b0 = 0.f, b1 = 0.f, b2 = 0.f, b3 = 0.f;
        const int c = cnt[p];
        for (int r = 0; r < c; ++r) {
            const float gx = rec[p * 6 + r].x;
            const float gy = rec[p * 6 + r].y;
            const int n = rn[p * 6 + r];
#pragma unroll
            for (int l = 0; l < 4; ++l) {
                const float wl = sw[p * 4 + l];
                const int Hl = HL[l], Wl = WL[l];
                const float fx = (gx + 1.0f) * 0.5f * (float)Wl - 0.5f;
                const float fy = (gy + 1.0f) * 0.5f * (float)Hl - 0.5f;
                if (!(fx >= -1.0f && fx < (float)Wl && fy >= -1.0f && fy < (float)Hl))
                    continue;
                const float x0f = floorf(fx), y0f = floorf(fy);
                const int x0 = (int)x0f, y0 = (int)y0f;
                const int x1 = x0 + 1, y1 = y0 + 1;
                const float wx1 = fx - x0f, wy1 = fy - y0f;
                const float wx0 = 1.0f - wx1, wy0 = 1.0f - wy1;
                const bool okx0 = (x0 >= 0), okx1 = (x1 < Wl);
                const bool oky0 = (y0 >= 0), oky1 = (y1 < Hl);
                const short* fb = fT[l] + (size_t)n * Hl * Wl * 132;
                if (okx0 && oky0) {
                    const float wt = wx0 * wy0 * wl;
                    const short* tp = fb + (size_t)(y0 * Wl + x0) * 132;
                    a0 = fmaf(bf2f(tp[tid]), wt, a0);
                    if (tid < 4) b0 = fmaf(bf2f(tp[128 + tid]), wt, b0);
                }
                if (okx1 && oky0) {
                    const float wt = wx1 * wy0 * wl;
                    const short* tp = fb + (size_t)(y0 * Wl + x1) * 132;
                    a1 = fmaf(bf2f(tp[tid]), wt, a1);
                    if (tid < 4) b1 = fmaf(bf2f(tp[128 + tid]), wt, b1);
                }
                if (okx0 && oky1) {
                    const float wt = wx0 * wy1 * wl;
                    const short* tp = fb + (size_t)(y1 * Wl + x0) * 132;
                    a2 = fmaf(bf2f(tp[tid]), wt, a2);
                    if (tid < 4) b2 = fmaf(bf2f(tp[128 + tid]), wt, b2);
                }
                if (okx1 && oky1) {
                    const float wt = wx1 * wy1 * wl;
                    const short* tp = fb + (size_t)(y1 * Wl + x1) * 132;
                    a3 = fmaf(bf2f(tp[tid]), wt, a3);
                    if (tid < 4) b3 = fmaf(bf2f(tp[128 + tid]), wt, b3);
                }
            }
        }
        acc[p]  = (a0 + a1) + (a2 + a3);
        accT[p] = (b0 + b1) + (b2 + b3);
    }

    if (tid < 4) {
#pragma unroll
        for (int p = 0; p < 8; ++p) tail[p * 4 + tid] = accT[p];
    }
    __syncthreads();

    float sf1 = 0.f, sf2 = 0.f;
#pragma unroll
    for (int p = 0; p < 8; ++p) {
        const float dx = rp[p * 3]     - tail[p * 4 + 0];
        const float dy = rp[p * 3 + 1] - tail[p * 4 + 1];
        const float dz = rp[p * 3 + 2] - tail[p * 4 + 2];
        const float wgt = expf(-0.1f * (dx * dx + dy * dy + dz * dz));
        sf1 += acc[p];
        sf2 += acc[p] * wgt;
    }
    const int y = pix / WID, x = pix % WID;
    const size_t po = ((size_t)(y + 1) * 102 + (x + 1)) * 256;
    sfo[po + tid]       = (short)f2bf(sf1);
    sfo[po + 128 + tid] = (short)f2bf(sf2);
}

// ---------------------------------------------------------------------------

extern "C" void kernel_launch(void* const* d_in, const int* in_sizes, int n_in,
                              void* d_out, int out_size, void* d_ws, size_t ws_size,
                              hipStream_t stream)
{
    const float* bev_query = (const float*)d_in[0];
    const float* bev_pos   = (const float*)d_in[1];
    const float* l2i       = (const float*)d_in[2];
    const float* feat0     = (const float*)d_in[3];
    const float* feat1     = (const float*)d_in[4];
    const float* feat2     = (const float*)d_in[5];
    const float* feat3     = (const float*)d_in[6];
    const float* in_w      = (const float*)d_in[7];
    const float* in_b      = (const float*)d_in[8];
    const float* off_w     = (const float*)d_in[9];
    const float* off_b     = (const float*)d_in[10];
    const float* sw_w      = (const float*)d_in[11];
    const float* sw_b      = (const float*)d_in[12];
    const float* mid_w1    = (const float*)d_in[13];
    const float* mid_b1    = (const float*)d_in[14];
    const float* mid_w2    = (const float*)d_in[15];
    const float* mid_b2    = (const float*)d_in[16];
    const float* mid_w3    = (const float*)d_in[17];
    const float* mid_b3    = (const float*)d_in[18];
    const float* out_w     = (const float*)d_in[19];
    const float* out_b     = (const float*)d_in[20];
    float* out = (float*)d_out;

    // ---- workspace layout (lifetime-aliased) ----
    float* ws    = (float*)d_ws;
    float* qn    = ws;                       // 1,280,000
    float* refp  = qn + 1280000;             //   240,000
    float* swts  = refp + 240000;            //   320,000
    float* E     = swts + 320000;            // 6,400,000 (slab5 | fTb+recs | m1_cl | slab3)
    float* F     = E + 6400000;              // 1,800,000 (xpadP+wpk1f | sf_cl | q2pad)
    float* H     = F + 1800000;              // 2,700,000 (m2_cl)
    short* wp_all= (short*)(H + 2700000);    // 2,441,216 sh

    float*  slab  = E;                       // conv1: 5 slabs; later convs: 3 slabs
    short*  fT0   = (short*)E;               // 2,962,080 shorts (bf16 feats)
    short*  fT1   = fT0 + 2230272;
    short*  fT2   = fT1 + 557568;
    short*  fT3   = fT2 + 139392;
    float2* recs  = (float2*)(E + 1600000);  // 480,000 f2
    int*    recn  = (int*)(E + 2560000);     // 480,000
    int*    cnts  = (int*)(E + 3040000);     //  80,000
    short*  m1_cl = (short*)E;               // 5,120,000 sh [100][100][512]
    float*  xpadP = F;                       // 1,384,448 f
    float*  wpk1f = F + 1384448;             //   409,600 f
    short*  sf_cl = (short*)F;               // 2,663,424 sh [102][102][256]
    short*  q2pad = (short*)F;               // 1,384,448 sh [104][104][128]
    short*  m2_cl = (short*)H;               // 5,326,848 sh [102][102][512]
    short*  wp_m1 = wp_all;                  // 1,179,648
    short*  wp_m2 = wp_m1 + 1179648;         //   262,144
    short*  wp_m3 = wp_m2 + 262144;          //   589,824
    short*  wp_out= wp_m3 + 589824;          //   409,600

    const dim3 blk(256);

    // ---- weight packing ----
    hipLaunchKernelGGL(pack_w1_f32, dim3(1600), blk, 0, stream, in_w, wpk1f);
    hipLaunchKernelGGL(pack_all_bf16, dim3(9536), blk, 0, stream,
                       mid_w1, mid_w2, mid_w3, out_w, wp_all);

    // ---- 1. q1 slabs = conv5x5_f32(bev_query), then qn = inorm(q1) fused ----
    hipLaunchKernelGGL(pad_xpad, dim3(5408), blk, 0, stream, bev_query, xpadP);
    hipLaunchKernelGGL(conv1_f32, dim3(4, 25, 5), blk, 0, stream, wpk1f, xpadP, slab);
    hipLaunchKernelGGL(red_norm_k<5>, dim3(128), blk, 0, stream, in_b, bev_query, slab, qn);

    // ---- 2. ref points + softmax weights + projection compaction ----
    hipLaunchKernelGGL(offsw_proj, dim3(HW), dim3(64), 0, stream,
                       qn, bev_pos, off_w, off_b, sw_w, sw_b, l2i,
                       refp, swts, recs, recn, cnts);

    // ---- 3. feature transposes -> bf16 (slab5 dead) ----
    hipLaunchKernelGGL(transpose_all, dim3(11571), blk, 0, stream,
                       feat0, feat1, feat2, feat3, fT0);

    // ---- 4. sampling -> sf_cl bf16 padded(1) ----
    hipMemsetAsync(sf_cl, 0, (size_t)2663424 * 2, stream);
    hipLaunchKernelGGL(sample_k2, dim3(HW), dim3(128), 0, stream,
                       refp, swts, recs, recn, cnts, fT0, fT1, fT2, fT3, sf_cl);

    // ---- 5. m1 = gelu(conv3x3 256->512) ----
    hipLaunchKernelGGL((mfma_conv<256, 3, 512, 1, true, 0, 100, 1>), dim3(4, 25, 4), blk, 0, stream,
                       wp_m1, sf_cl, mid_b1, nullptr, m1_cl);
    // ---- 6. m2 = gelu(conv1x1 512->512) -> padded(1) ----
    hipMemsetAsync(m2_cl, 0, (size_t)5326848 * 2, stream);
    hipLaunchKernelGGL((mfma_conv<512, 1, 512, 1, true, 1, 102, 1>), dim3(4, 25, 4), blk, 0, stream,
                       wp_m2, m1_cl, mid_b2, nullptr, m2_cl);
    // ---- 7. q2 = inorm(qn + conv3x3 512->128) ----
    hipLaunchKernelGGL((mfma_conv<512, 3, 128, 2, false, 0, 0, 3>), dim3(1, 25, 12), blk, 0, stream,
                       wp_m3, m2_cl, mid_b3, slab, nullptr);
    hipLaunchKernelGGL(red_norm_k<3>, dim3(128), blk, 0, stream, mid_b3, qn, slab, qn);
    // ---- 8. q3 = inorm(qn + conv5x5 bf16) ----
    hipLaunchKernelGGL((pad_cl_cast<128, 2>), dim3(5411), blk, 0, stream, qn, q2pad);
    hipLaunchKernelGGL((mfma_conv<128, 5, 128, 2, false, 0, 0, 3>), dim3(1, 25, 12), blk, 0, stream,
                       wp_out, q2pad, out_b, slab, nullptr);
    hipLaunchKernelGGL(red_norm_k<3>, dim3(128), blk, 0, stream, out_b, qn, slab, out);
}

// Round 10
// 814.459 us; speedup vs baseline: 1.0608x; 1.0037x over previous
//
#include <hip/hip_runtime.h>
#include <cstddef>

// ---------------------------------------------------------------------------
// SegTransformerDecoder — round 10 (round 9 + sample_k3 tap-precompute).
//  * sample_k3: phase 1 computes each (p,rec,level) tap descriptor ONCE
//    (distributed over threads, stored in LDS); phase 2 is pure gather+FMA.
//    OOB taps get weight 0 (reference semantics) — bitwise-identical sums.
// ---------------------------------------------------------------------------

#define HW   10000
#define WID  100

typedef __attribute__((ext_vector_type(8))) __bf16 bf16x8;
typedef __attribute__((ext_vector_type(4))) float f32x4;
typedef __attribute__((ext_vector_type(4))) unsigned int uint4v;

__device__ __forceinline__ float gelu_exact(float x) {
    return 0.5f * x * (1.0f + erff(x * 0.7071067811865475f));
}
__device__ __forceinline__ unsigned short f2bf(float v) {
    unsigned int b = __float_as_uint(v);
    return (unsigned short)((b + 0x7FFFu + ((b >> 16) & 1u)) >> 16);
}
__device__ __forceinline__ float bf2f(short s) {
    return __uint_as_float(((unsigned int)(unsigned short)s) << 16);
}
__device__ __forceinline__ bf16x8 load_frag(const short* p) {
    return __builtin_bit_cast(bf16x8, *(const uint4v*)p);
}

// ---------------------------------------------------------------------------
// conv1_f32 v4 (decision chain, exact fp32) — unchanged from round 9.
// ---------------------------------------------------------------------------
__global__ __launch_bounds__(256)
void conv1_f32(const float* __restrict__ wpkf, const float* __restrict__ xpadP,
               float* __restrict__ slab)
{
    __shared__ float As[2048];      // [ic 16][oc 128]
    __shared__ float Bs[2048];      // [ic 16][pix 128]
    const int t  = threadIdx.x;
    const int og = t >> 4;
    const int pg = t & 15;
    const int x0 = blockIdx.x * 32, y0 = blockIdx.y * 4;
    const int ky = blockIdx.z;

    const int e0 = t * 4, e1 = 1024 + t * 4;
    const int ica = e0 >> 7, pa = e0 & 127;
    const int icb = e1 >> 7, pb = e1 & 127;
    const int rowa = (y0 + (pa >> 5) + ky) * 104 + x0 + (pa & 31);
    const int rowb = (y0 + (pb >> 5) + ky) * 104 + x0 + (pb & 31);

    float acc[8][8];
#pragma unroll
    for (int i = 0; i < 8; ++i)
#pragma unroll
        for (int j = 0; j < 8; ++j) acc[i][j] = 0.f;

    for (int kx = 0; kx < 5; ++kx) {
        for (int ic0 = 0; ic0 < 128; ic0 += 16) {
            __syncthreads();
            const float* asrc = wpkf + (size_t)((ky * 5 + kx) * 128 + ic0) * 128;
            *(float4*)(As + e0) = *(const float4*)(asrc + e0);
            *(float4*)(As + e1) = *(const float4*)(asrc + e1);
            float4 bva, bvb;
            __builtin_memcpy(&bva, xpadP + (size_t)(ic0 + ica) * 10816 + rowa + kx, 16);
            __builtin_memcpy(&bvb, xpadP + (size_t)(ic0 + icb) * 10816 + rowb + kx, 16);
            *(float4*)(Bs + e0) = bva;
            *(float4*)(Bs + e1) = bvb;
            __syncthreads();
#pragma unroll
            for (int k = 0; k < 16; ++k) {
                float a[8], b[8];
                *(float4*)(a)     = *(float4*)(As + k * 128 + og * 8);
                *(float4*)(a + 4) = *(float4*)(As + k * 128 + og * 8 + 4);
                *(float4*)(b)     = *(float4*)(Bs + k * 128 + pg * 4);
                *(float4*)(b + 4) = *(float4*)(Bs + k * 128 + 64 + pg * 4);
#pragma unroll
                for (int i = 0; i < 8; ++i)
#pragma unroll
                    for (int j = 0; j < 8; ++j)
                        acc[i][j] = fmaf(a[i], b[j], acc[i][j]);
            }
        }
    }

    float* sl = slab + (size_t)ky * 1280000;
#pragma unroll
    for (int h = 0; h < 2; ++h) {
        const int p  = h * 64 + pg * 4;
        const int py = y0 + (p >> 5);
        const int px = x0 + (p & 31);
        if (px >= 100) continue;
#pragma unroll
        for (int i = 0; i < 8; ++i) {
            float* dst = sl + (size_t)(og * 8 + i) * HW + py * WID + px;
            __builtin_memcpy(dst, &acc[i][h * 4], 16);
        }
    }
}

// ---------------------------------------------------------------------------
// bf16 MFMA implicit-GEMM conv (unchanged).
// ---------------------------------------------------------------------------
template<int CIN, int KS, int COUT, int EPI, bool ACT, int OPAD, int OPW, int KSPLIT>
__global__ __launch_bounds__(256)
void mfma_conv(const short* __restrict__ wpk, const short* __restrict__ xcl,
               const float* __restrict__ bias,
               float* __restrict__ outcm, short* __restrict__ outcl)
{
    constexpr int PW = 100 + 2 * (KS / 2);
    constexpr int CHUNK = (KS + KSPLIT - 1) / KSPLIT;
    const int lane = threadIdx.x & 63;
    const int wave = threadIdx.x >> 6;
    const int wr = wave >> 1;
    const int wc = wave & 1;
    const int lq = lane >> 4;
    const int ln = lane & 15;

    const int oc0 = blockIdx.x * 128;
    const int y0  = blockIdx.y * 4;
    const int zb  = blockIdx.z;
    const int bx  = (KSPLIT > 1) ? (zb & 3) : zb;
    const int ks  = (KSPLIT > 1) ? (zb >> 2) : 0;
    const int x0  = bx * 32;
    const int ky_lo = ks * CHUNK;
    const int ky_hi = (ky_lo + CHUNK < KS) ? ky_lo + CHUNK : KS;

    int bpix[4];
#pragma unroll
    for (int nt = 0; nt < 4; ++nt) {
        const int nl = wc * 64 + nt * 16 + ln;
        bpix[nt] = (y0 + (nl >> 5)) * PW + (x0 + (nl & 31));
    }

    f32x4 acc[4][4];
#pragma unroll
    for (int mt = 0; mt < 4; ++mt)
#pragma unroll
        for (int nt = 0; nt < 4; ++nt)
#pragma unroll
            for (int r = 0; r < 4; ++r) acc[mt][nt][r] = 0.f;

    const int arow0 = oc0 + wr * 64 + ln;

    for (int ky = ky_lo; ky < ky_hi; ++ky) {
#pragma unroll
        for (int kx = 0; kx < KS; ++kx) {
            const short* wsl = wpk + (size_t)((ky * KS + kx) * COUT) * CIN;
            const short* xsl = xcl + (size_t)(ky * PW + kx) * CIN;
            for (int ic0 = 0; ic0 < CIN; ic0 += 32) {
                bf16x8 a[4], b[4];
#pragma unroll
                for (int mt = 0; mt < 4; ++mt)
                    a[mt] = load_frag(wsl + (size_t)(arow0 + mt * 16) * CIN + ic0 + lq * 8);
#pragma unroll
                for (int nt = 0; nt < 4; ++nt)
                    b[nt] = load_frag(xsl + (size_t)bpix[nt] * CIN + ic0 + lq * 8);
#pragma unroll
                for (int mt = 0; mt < 4; ++mt)
#pragma unroll
                    for (int nt = 0; nt < 4; ++nt)
                        acc[mt][nt] = __builtin_amdgcn_mfma_f32_16x16x32_bf16(
                            a[mt], b[nt], acc[mt][nt], 0, 0, 0);
            }
        }
    }

#pragma unroll
    for (int mt = 0; mt < 4; ++mt) {
        const int ocr = oc0 + wr * 64 + mt * 16 + lq * 4;
        float bb[4];
        if (EPI == 1) {
            const float4 bv = *(const float4*)(bias + ocr);
            bb[0] = bv.x; bb[1] = bv.y; bb[2] = bv.z; bb[3] = bv.w;
        }
#pragma unroll
        for (int nt = 0; nt < 4; ++nt) {
            const int nl = wc * 64 + nt * 16 + ln;
            const int x = x0 + (nl & 31);
            const int y = y0 + (nl >> 5);
            if (x >= 100) continue;
            if (EPI == 1) {
                float v[4];
#pragma unroll
                for (int r = 0; r < 4; ++r) {
                    float t = acc[mt][nt][r] + bb[r];
                    if (ACT) t = gelu_exact(t);
                    v[r] = t;
                }
                ushort4 pk;
                pk.x = f2bf(v[0]); pk.y = f2bf(v[1]); pk.z = f2bf(v[2]); pk.w = f2bf(v[3]);
                *(ushort4*)(outcl + ((size_t)(y + OPAD) * OPW + (x + OPAD)) * COUT + ocr) = pk;
            } else {
                const int pix = y * WID + x;
#pragma unroll
                for (int r = 0; r < 4; ++r)
                    outcm[((size_t)ks * COUT + ocr + r) * HW + pix] = acc[mt][nt][r];
            }
        }
    }
}

// fused: out = inorm(bias + res + sum_z slab[z])
template<int NS>
__global__ __launch_bounds__(256)
void red_norm_k(const float* __restrict__ bias, const float* __restrict__ res,
                const float* __restrict__ slab, float* __restrict__ outp)
{
    const int c = blockIdx.x, tid = threadIdx.x;
    const size_t base = (size_t)c * HW;
    const float bc = bias[c];
    float v[40];
    float s1 = 0.f, s2 = 0.f;
#pragma unroll
    for (int k = 0; k < 40; ++k) {
        const int i = tid + k * 256;
        float x = 0.f;
        if (i < HW) {
            x = bc + res[base + i];
#pragma unroll
            for (int z = 0; z < NS; ++z) x += slab[(size_t)z * 1280000 + base + i];
            s1 += x; s2 += x * x;
        }
        v[k] = x;
    }
    __shared__ float r1[256], r2[256];
    r1[tid] = s1; r2[tid] = s2; __syncthreads();
    for (int o = 128; o > 0; o >>= 1) {
        if (tid < o) { r1[tid] += r1[tid + o]; r2[tid] += r2[tid + o]; }
        __syncthreads();
    }
    const float mean = r1[0] * 1e-4f;
    const float var  = fmaxf(r2[0] * 1e-4f - mean * mean, 0.f);
    const float rstd = rsqrtf(var + 1e-5f);
#pragma unroll
    for (int k = 0; k < 40; ++k) {
        const int i = tid + k * 256;
        if (i < HW) outp[base + i] = (v[k] - mean) * rstd;
    }
}

// fp32 channel-major [128][100][100] -> channel-major padded(2) [128][104][104]
__global__ void pad_xpad(const float* __restrict__ in, float* __restrict__ out)
{
    const int total = 128 * 104 * 104;
    for (int i = blockIdx.x * blockDim.x + threadIdx.x; i < total; i += gridDim.x * blockDim.x) {
        const int c = i / 10816;
        const int r = i % 10816;
        const int y = r / 104 - 2;
        const int x = r % 104 - 2;
        float v = 0.f;
        if (x >= 0 && x < 100 && y >= 0 && y < 100) v = in[(size_t)c * HW + y * WID + x];
        out[i] = v;
    }
}

template<int C, int PAD>
__global__ void pad_cl_cast(const float* __restrict__ in, short* __restrict__ out)
{
    constexpr int PW = 100 + 2 * PAD;
    const int total = PW * PW * C;
    for (int i = blockIdx.x * blockDim.x + threadIdx.x; i < total; i += gridDim.x * blockDim.x) {
        const int c = i % C;
        const int p = i / C;
        const int x = p % PW - PAD;
        const int y = p / PW - PAD;
        float v = 0.f;
        if (x >= 0 && x < 100 && y >= 0 && y < 100) v = in[(size_t)c * HW + y * WID + x];
        out[i] = (short)f2bf(v);
    }
}

__global__ void pack_all_bf16(const float* __restrict__ w1, const float* __restrict__ w2,
                              const float* __restrict__ w3, const float* __restrict__ w4,
                              short* __restrict__ out)
{
    const int E0 = 1179648, E1 = E0 + 262144, E2 = E1 + 589824, E3 = E2 + 409600;
    for (int i = blockIdx.x * blockDim.x + threadIdx.x; i < E3; i += gridDim.x * blockDim.x) {
        const float* w; int OC, CI, KS, j;
        if (i < E0)      { w = w1; OC = 512; CI = 256; KS = 3; j = i; }
        else if (i < E1) { w = w2; OC = 512; CI = 512; KS = 1; j = i - E0; }
        else if (i < E2) { w = w3; OC = 128; CI = 512; KS = 3; j = i - E1; }
        else             { w = w4; OC = 128; CI = 128; KS = 5; j = i - E2; }
        const int ic = j % CI;
        int t = j / CI;
        const int oc = t % OC;
        const int s = t / OC;
        const int ky = s / KS, kx = s % KS;
        out[i] = (short)f2bf(w[(((size_t)oc * CI + ic) * KS + ky) * KS + kx]);
    }
}

__global__ void pack_w1_f32(const float* __restrict__ w, float* __restrict__ out)
{
    const int total = 128 * 128 * 25;
    for (int i = blockIdx.x * blockDim.x + threadIdx.x; i < total; i += gridDim.x * blockDim.x) {
        const int oc = i % 128;
        int t = i / 128;
        const int ic = t % 128;
        const int s = t / 128;
        const int ky = s / 5, kx = s % 5;
        out[i] = w[(((size_t)oc * 128 + ic) * 5 + ky) * 5 + kx];
    }
}

// feature transposes -> bf16 channel-last, concatenated
__global__ void transpose_all(const float* __restrict__ f0, const float* __restrict__ f1,
                              const float* __restrict__ f2, const float* __restrict__ f3,
                              short* __restrict__ out)
{
    const int O1 = 2230272, O2 = O1 + 557568, O3 = O2 + 139392, O4 = O3 + 34848;
    for (int i = blockIdx.x * blockDim.x + threadIdx.x; i < O4; i += gridDim.x * blockDim.x) {
        const float* f; int Hl, Wl, j;
        if (i < O1)      { f = f0; Hl = 32; Wl = 88; j = i; }
        else if (i < O2) { f = f1; Hl = 16; Wl = 44; j = i - O1; }
        else if (i < O3) { f = f2; Hl = 8;  Wl = 22; j = i - O2; }
        else             { f = f3; Hl = 4;  Wl = 11; j = i - O3; }
        const int c = j % 132;
        int t = j / 132;
        const int x = t % Wl; t /= Wl;
        const int y = t % Hl; t /= Hl;
        const int n = t;
        out[i] = (short)f2bf(f[(((size_t)n * 132 + c) * Hl + y) * Wl + x]);
    }
}

// offsw + projection compaction fused (unchanged)
__global__ __launch_bounds__(64)
void offsw_proj(const float* __restrict__ qn, const float* __restrict__ bev_pos,
                const float* __restrict__ off_w, const float* __restrict__ off_b,
                const float* __restrict__ sw_w, const float* __restrict__ sw_b,
                const float* __restrict__ l2i,
                float* __restrict__ refp, float* __restrict__ swts,
                float2* __restrict__ recs, int* __restrict__ recn, int* __restrict__ cnts)
{
    const int pix = blockIdx.x;
    const int tid = threadIdx.x;
    __shared__ float qv[128];
    __shared__ float swraw[32];
    __shared__ float rp[24];
    qv[tid]      = qn[(size_t)tid * HW + pix];
    qv[tid + 64] = qn[(size_t)(tid + 64) * HW + pix];
    __syncthreads();

    if (tid < 24) {
        float acc = off_b[tid];
        for (int c = 0; c < 128; ++c) acc = fmaf(qv[c], off_w[tid * 128 + c], acc);
        const float s = 1.0f / (1.0f + expf(-acc));
        const int coord = tid % 3;
        const float rng = (coord < 2) ? 0.250001f : 4.000001f;
        const float v = s * rng * 2.0f - rng;
        const float lo[3]   = {-50.f, -50.f, -5.f};
        const float span[3] = {100.f, 100.f, 8.f};
        const float rv = bev_pos[pix * 3 + coord] * span[coord] + lo[coord] + v;
        refp[pix * 24 + tid] = rv;
        rp[tid] = rv;
    } else if (tid >= 32) {
        const int j = tid - 32;
        float acc = sw_b[j];
        for (int c = 0; c < 128; ++c) acc = fmaf(qv[c], sw_w[j * 128 + c], acc);
        swraw[j] = acc;
    }
    __syncthreads();
    if (tid < 8) {
        float m = -1e30f;
#pragma unroll
        for (int l = 0; l < 4; ++l) m = fmaxf(m, swraw[tid * 4 + l]);
        float e[4], sum = 0.f;
#pragma unroll
        for (int l = 0; l < 4; ++l) { e[l] = expf(swraw[tid * 4 + l] - m); sum += e[l]; }
        const float inv = 1.0f / sum;
#pragma unroll
        for (int l = 0; l < 4; ++l) swts[pix * 32 + tid * 4 + l] = e[l] * inv;
    }

    bool keep = false;
    float gx = -2.f, gy = -2.f;
    int p = 0, n = 0;
    if (tid < 48) {
        p = tid / 6;
        n = tid - p * 6;
        const float X = rp[p * 3 + 0], Y = rp[p * 3 + 1], Z = rp[p * 3 + 2];
        const float* m = l2i + n * 16;
        const float cx = m[0] * X + m[1] * Y + m[2]  * Z + m[3];
        const float cy = m[4] * X + m[5] * Y + m[6]  * Z + m[7];
        const float cz = m[8] * X + m[9] * Y + m[10] * Z + m[11];
        const bool valid = cz > 1e-5f;
        const float zz = fmaxf(cz, 1e-5f);
        gx = valid ? (cx / zz) * (2.0f / 704.0f) - 1.0f : -2.0f;
        gy = valid ? (cy / zz) * (2.0f / 256.0f) - 1.0f : -2.0f;
        keep = (gx > -1.092f) && (gx < 1.092f) && (gy > -1.26f) && (gy < 1.26f);
    }
    const unsigned long long bm = __ballot(keep);
    if (keep) {
        const unsigned long long gmask = 0x3Full << (p * 6);
        const int slot = __popcll(bm & ((1ull << tid) - 1ull) & gmask);
        recs[(size_t)pix * 48 + p * 6 + slot] = make_float2(gx, gy);
        recn[(size_t)pix * 48 + p * 6 + slot] = n;
    }
    if (tid < 48 && (tid % 6) == 0) {
        const unsigned long long gmask = 0x3Full << (p * 6);
        cnts[pix * 8 + p] = __popcll(bm & gmask);
    }
}

// ---------------------------------------------------------------------------
// sample_k3: phase-1 tap precompute in LDS (once per (p,rec,level)), phase-2
// pure gather+FMA. OOB taps have weight 0 (reference tap semantics).
// ---------------------------------------------------------------------------
__global__ __launch_bounds__(128)
void sample_k3(const float* __restrict__ refp, const float* __restrict__ swts,
               const float2* __restrict__ recs, const int* __restrict__ recn,
               const int* __restrict__ cnts,
               const short* __restrict__ fb0,   // concatenated bf16 feats (fT0 base)
               short* __restrict__ sfo)
{
    const int pix = blockIdx.x;
    const int tid = threadIdx.x;                   // 128
    __shared__ float rp[24], sw[32], tail[32];
    __shared__ float2 rec[48];
    __shared__ int rn[48];
    __shared__ int cnt[8];
    __shared__ int4   toff[192];
    __shared__ float4 twt[192];
    if (tid < 24) rp[tid] = refp[pix * 24 + tid];
    if (tid < 32) sw[tid] = swts[pix * 32 + tid];
    if (tid < 48) { rec[tid] = recs[(size_t)pix * 48 + tid]; rn[tid] = recn[(size_t)pix * 48 + tid]; }
    if (tid < 8)  cnt[tid] = cnts[pix * 8 + tid];
    __syncthreads();

    const int HL[4] = {32, 16, 8, 4};
    const int WL[4] = {88, 44, 22, 11};
    const int LB[4] = {0, 2230272, 2787840, 2927232};   // level bases (shorts)

    // ---- phase 1: tap descriptors, one entry per (p, rec, level) ----
    for (int e = tid; e < 192; e += 128) {
        const int p  = e / 24;
        const int rl = e - p * 24;
        const int r  = rl >> 2;
        const int l  = rl & 3;
        int4 off = make_int4(0, 0, 0, 0);
        float4 wt = make_float4(0.f, 0.f, 0.f, 0.f);
        if (r < cnt[p]) {
            const float gx = rec[p * 6 + r].x;
            const float gy = rec[p * 6 + r].y;
            const int   n  = rn[p * 6 + r];
            const float wl = sw[p * 4 + l];
            const int Hl = HL[l], Wl = WL[l];
            const float fx = (gx + 1.0f) * 0.5f * (float)Wl - 0.5f;
            const float fy = (gy + 1.0f) * 0.5f * (float)Hl - 0.5f;
            if (fx >= -1.0f && fx < (float)Wl && fy >= -1.0f && fy < (float)Hl) {
                const float x0f = floorf(fx), y0f = floorf(fy);
                const int x0 = (int)x0f, y0 = (int)y0f;
                const int x1 = x0 + 1, y1 = y0 + 1;
                const float wx1 = fx - x0f, wy1 = fy - y0f;
                const float wx0 = 1.0f - wx1, wy0 = 1.0f - wy1;
                const bool okx0 = (x0 >= 0), okx1 = (x1 < Wl);
                const bool oky0 = (y0 >= 0), oky1 = (y1 < Hl);
                const int xc0 = okx0 ? x0 : 0, xc1 = okx1 ? x1 : Wl - 1;
                const int yc0 = oky0 ? y0 : 0, yc1 = oky1 ? y1 : Hl - 1;
                const int base = LB[l] + n * Hl * Wl * 132;
                off.x = base + (yc0 * Wl + xc0) * 132;
                off.y = base + (yc0 * Wl + xc1) * 132;
                off.z = base + (yc1 * Wl + xc0) * 132;
                off.w = base + (yc1 * Wl + xc1) * 132;
                wt.x = (okx0 && oky0) ? wx0 * wy0 * wl : 0.f;
                wt.y = (okx1 && oky0) ? wx1 * wy0 * wl : 0.f;
                wt.z = (okx0 && oky1) ? wx0 * wy1 * wl : 0.f;
                wt.w = (okx1 && oky1) ? wx1 * wy1 * wl : 0.f;
            }
        }
        toff[e] = off;
        twt[e]  = wt;
    }
    __syncthreads();

    // ---- phase 2: gather + FMA only ----
    float acc[8], accT[8];
#pragma unroll
    for (int p = 0; p < 8; ++p) {
        float a0 = 0.f, a1 = 0.f, a2 = 0.f, a3 = 0.f;
        float b0 = 0.f, b1 = 0.f, b2 = 0.f, b3 = 0.f;
        const int c = cnt[p];
        for (int r = 0; r < c; ++r) {
            const int eb = p * 24 + r * 4;
#pragma unroll
            for (int l = 0; l < 4; ++l) {
                const int4   off = toff[eb + l];
                const float4 wt  = twt[eb + l];
                a0 = fmaf(bf2f(fb0[off.x + tid]), wt.x, a0);
                a1 = fmaf(bf2f(fb0[off.y + tid]), wt.y, a1);
                a2 = fmaf(bf2f(fb0[off.z + tid]), wt.z, a2);
                a3 = fmaf(bf2f(fb0[off.w + tid]), wt.w, a3);
                if (tid < 4) {
                    b0 = fmaf(bf2f(fb0[off.x + 128 + tid]), wt.x, b0);
                    b1 = fmaf(bf2f(fb0[off.y + 128 + tid]), wt.y, b1);
                    b2 = fmaf(bf2f(fb0[off.z + 128 + tid]), wt.z, b2);
                    b3 = fmaf(bf2f(fb0[off.w + 128 + tid]), wt.w, b3);
                }
            }
        }
        acc[p]  = (a0 + a1) + (a2 + a3);
        accT[p] = (b0 + b1) + (b2 + b3);
    }

    if (tid < 4) {
#pragma unroll
        for (int p = 0; p < 8; ++p) tail[p * 4 + tid] = accT[p];
    }
    __syncthreads();

    float sf1 = 0.f, sf2 = 0.f;
#pragma unroll
    for (int p = 0; p < 8; ++p) {
        const float dx = rp[p * 3]     - tail[p * 4 + 0];
        const float dy = rp[p * 3 + 1] - tail[p * 4 + 1];
        const float dz = rp[p * 3 + 2] - tail[p * 4 + 2];
        const float wgt = expf(-0.1f * (dx * dx + dy * dy + dz * dz));
        sf1 += acc[p];
        sf2 += acc[p] * wgt;
    }
    const int y = pix / WID, x = pix % WID;
    const size_t po = ((size_t)(y + 1) * 102 + (x + 1)) * 256;
    sfo[po + tid]       = (short)f2bf(sf1);
    sfo[po + 128 + tid] = (short)f2bf(sf2);
}

// ---------------------------------------------------------------------------

extern "C" void kernel_launch(void* const* d_in, const int* in_sizes, int n_in,
                              void* d_out, int out_size, void* d_ws, size_t ws_size,
                              hipStream_t stream)
{
    const float* bev_query = (const float*)d_in[0];
    const float* bev_pos   = (const float*)d_in[1];
    const float* l2i       = (const float*)d_in[2];
    const float* feat0     = (const float*)d_in[3];
    const float* feat1     = (const float*)d_in[4];
    const float* feat2     = (const float*)d_in[5];
    const float* feat3     = (const float*)d_in[6];
    const float* in_w      = (const float*)d_in[7];
    const float* in_b      = (const float*)d_in[8];
    const float* off_w     = (const float*)d_in[9];
    const float* off_b     = (const float*)d_in[10];
    const float* sw_w      = (const float*)d_in[11];
    const float* sw_b      = (const float*)d_in[12];
    const float* mid_w1    = (const float*)d_in[13];
    const float* mid_b1    = (const float*)d_in[14];
    const float* mid_w2    = (const float*)d_in[15];
    const float* mid_b2    = (const float*)d_in[16];
    const float* mid_w3    = (const float*)d_in[17];
    const float* mid_b3    = (const float*)d_in[18];
    const float* out_w     = (const float*)d_in[19];
    const float* out_b     = (const float*)d_in[20];
    float* out = (float*)d_out;

    // ---- workspace layout (lifetime-aliased) ----
    float* ws    = (float*)d_ws;
    float* qn    = ws;                       // 1,280,000
    float* refp  = qn + 1280000;             //   240,000
    float* swts  = refp + 240000;            //   320,000
    float* E     = swts + 320000;            // 6,400,000 (slab5 | fTb+recs | m1_cl | slab3)
    float* F     = E + 6400000;              // 1,800,000 (xpadP+wpk1f | sf_cl | q2pad)
    float* H     = F + 1800000;              // 2,700,000 (m2_cl)
    short* wp_all= (short*)(H + 2700000);    // 2,441,216 sh

    float*  slab  = E;                       // conv1: 5 slabs; later convs: 3 slabs
    short*  fT0   = (short*)E;               // 2,962,080 shorts (bf16 feats, concatenated)
    float2* recs  = (float2*)(E + 1600000);  // 480,000 f2
    int*    recn  = (int*)(E + 2560000);     // 480,000
    int*    cnts  = (int*)(E + 3040000);     //  80,000
    short*  m1_cl = (short*)E;               // 5,120,000 sh [100][100][512]
    float*  xpadP = F;                       // 1,384,448 f
    float*  wpk1f = F + 1384448;             //   409,600 f
    short*  sf_cl = (short*)F;               // 2,663,424 sh [102][102][256]
    short*  q2pad = (short*)F;               // 1,384,448 sh [104][104][128]
    short*  m2_cl = (short*)H;               // 5,326,848 sh [102][102][512]
    short*  wp_m1 = wp_all;                  // 1,179,648
    short*  wp_m2 = wp_m1 + 1179648;         //   262,144
    short*  wp_m3 = wp_m2 + 262144;          //   589,824
    short*  wp_out= wp_m3 + 589824;          //   409,600

    const dim3 blk(256);

    // ---- weight packing ----
    hipLaunchKernelGGL(pack_w1_f32, dim3(1600), blk, 0, stream, in_w, wpk1f);
    hipLaunchKernelGGL(pack_all_bf16, dim3(9536), blk, 0, stream,
                       mid_w1, mid_w2, mid_w3, out_w, wp_all);

    // ---- 1. q1 slabs = conv5x5_f32(bev_query), then qn = inorm(q1) fused ----
    hipLaunchKernelGGL(pad_xpad, dim3(5408), blk, 0, stream, bev_query, xpadP);
    hipLaunchKernelGGL(conv1_f32, dim3(4, 25, 5), blk, 0, stream, wpk1f, xpadP, slab);
    hipLaunchKernelGGL(red_norm_k<5>, dim3(128), blk, 0, stream, in_b, bev_query, slab, qn);

    // ---- 2. ref points + softmax weights + projection compaction ----
    hipLaunchKernelGGL(offsw_proj, dim3(HW), dim3(64), 0, stream,
                       qn, bev_pos, off_w, off_b, sw_w, sw_b, l2i,
                       refp, swts, recs, recn, cnts);

    // ---- 3. feature transposes -> bf16 (slab5 dead) ----
    hipLaunchKernelGGL(transpose_all, dim3(11571), blk, 0, stream,
                       feat0, feat1, feat2, feat3, fT0);

    // ---- 4. sampling -> sf_cl bf16 padded(1) ----
    hipMemsetAsync(sf_cl, 0, (size_t)2663424 * 2, stream);
    hipLaunchKernelGGL(sample_k3, dim3(HW), dim3(128), 0, stream,
                       refp, swts, recs, recn, cnts, fT0, sf_cl);

    // ---- 5. m1 = gelu(conv3x3 256->512) ----
    hipLaunchKernelGGL((mfma_conv<256, 3, 512, 1, true, 0, 100, 1>), dim3(4, 25, 4), blk, 0, stream,
                       wp_m1, sf_cl, mid_b1, nullptr, m1_cl);
    // ---- 6. m2 = gelu(conv1x1 512->512) -> padded(1) ----
    hipMemsetAsync(m2_cl, 0, (size_t)5326848 * 2, stream);
    hipLaunchKernelGGL((mfma_conv<512, 1, 512, 1, true, 1, 102, 1>), dim3(4, 25, 4), blk, 0, stream,
                       wp_m2, m1_cl, mid_b2, nullptr, m2_cl);
    // ---- 7. q2 = inorm(qn + conv3x3 512->128) ----
    hipLaunchKernelGGL((mfma_conv<512, 3, 128, 2, false, 0, 0, 3>), dim3(1, 25, 12), blk, 0, stream,
                       wp_m3, m2_cl, mid_b3, slab, nullptr);
    hipLaunchKernelGGL(red_norm_k<3>, dim3(128), blk, 0, stream, mid_b3, qn, slab, qn);
    // ---- 8. q3 = inorm(qn + conv5x5 bf16) ----
    hipLaunchKernelGGL((pad_cl_cast<128, 2>), dim3(5411), blk, 0, stream, qn, q2pad);
    hipLaunchKernelGGL((mfma_conv<128, 5, 128, 2, false, 0, 0, 3>), dim3(1, 25, 12), blk, 0, stream,
                       wp_out, q2pad, out_b, slab, nullptr);
    hipLaunchKernelGGL(red_norm_k<3>, dim3(128), blk, 0, stream, out_b, qn, slab, out);
}

// Round 11
// 784.187 us; speedup vs baseline: 1.1018x; 1.0386x over previous
//
#include <hip/hip_runtime.h>
#include <cstddef>

// ---------------------------------------------------------------------------
// SegTransformerDecoder — round 11 (round 10 + sample_k4).
//  * sample_k4: 64-lane wave per pixel; each lane owns 2 adjacent channels
//    via one ushort2 load (packed bf16->f32 exact); tap offsets readfirstlane'd
//    to SGPRs (saddr gathers, no per-lane addr VALU). ~1.6x fewer VALU issues
//    per tap; per-channel accumulation order unchanged (bit-identical).
// ---------------------------------------------------------------------------

#define HW   10000
#define WID  100

typedef __attribute__((ext_vector_type(8))) __bf16 bf16x8;
typedef __attribute__((ext_vector_type(4))) float f32x4;
typedef __attribute__((ext_vector_type(4))) unsigned int uint4v;

__device__ __forceinline__ float gelu_exact(float x) {
    return 0.5f * x * (1.0f + erff(x * 0.7071067811865475f));
}
__device__ __forceinline__ unsigned short f2bf(float v) {
    unsigned int b = __float_as_uint(v);
    return (unsigned short)((b + 0x7FFFu + ((b >> 16) & 1u)) >> 16);
}
__device__ __forceinline__ float bf2f(short s) {
    return __uint_as_float(((unsigned int)(unsigned short)s) << 16);
}
__device__ __forceinline__ bf16x8 load_frag(const short* p) {
    return __builtin_bit_cast(bf16x8, *(const uint4v*)p);
}

// ---------------------------------------------------------------------------
// conv1_f32 v4 (decision chain, exact fp32) — unchanged from round 9.
// ---------------------------------------------------------------------------
__global__ __launch_bounds__(256)
void conv1_f32(const float* __restrict__ wpkf, const float* __restrict__ xpadP,
               float* __restrict__ slab)
{
    __shared__ float As[2048];      // [ic 16][oc 128]
    __shared__ float Bs[2048];      // [ic 16][pix 128]
    const int t  = threadIdx.x;
    const int og = t >> 4;
    const int pg = t & 15;
    const int x0 = blockIdx.x * 32, y0 = blockIdx.y * 4;
    const int ky = blockIdx.z;

    const int e0 = t * 4, e1 = 1024 + t * 4;
    const int ica = e0 >> 7, pa = e0 & 127;
    const int icb = e1 >> 7, pb = e1 & 127;
    const int rowa = (y0 + (pa >> 5) + ky) * 104 + x0 + (pa & 31);
    const int rowb = (y0 + (pb >> 5) + ky) * 104 + x0 + (pb & 31);

    float acc[8][8];
#pragma unroll
    for (int i = 0; i < 8; ++i)
#pragma unroll
        for (int j = 0; j < 8; ++j) acc[i][j] = 0.f;

    for (int kx = 0; kx < 5; ++kx) {
        for (int ic0 = 0; ic0 < 128; ic0 += 16) {
            __syncthreads();
            const float* asrc = wpkf + (size_t)((ky * 5 + kx) * 128 + ic0) * 128;
            *(float4*)(As + e0) = *(const float4*)(asrc + e0);
            *(float4*)(As + e1) = *(const float4*)(asrc + e1);
            float4 bva, bvb;
            __builtin_memcpy(&bva, xpadP + (size_t)(ic0 + ica) * 10816 + rowa + kx, 16);
            __builtin_memcpy(&bvb, xpadP + (size_t)(ic0 + icb) * 10816 + rowb + kx, 16);
            *(float4*)(Bs + e0) = bva;
            *(float4*)(Bs + e1) = bvb;
            __syncthreads();
#pragma unroll
            for (int k = 0; k < 16; ++k) {
                float a[8], b[8];
                *(float4*)(a)     = *(float4*)(As + k * 128 + og * 8);
                *(float4*)(a + 4) = *(float4*)(As + k * 128 + og * 8 + 4);
                *(float4*)(b)     = *(float4*)(Bs + k * 128 + pg * 4);
                *(float4*)(b + 4) = *(float4*)(Bs + k * 128 + 64 + pg * 4);
#pragma unroll
                for (int i = 0; i < 8; ++i)
#pragma unroll
                    for (int j = 0; j < 8; ++j)
                        acc[i][j] = fmaf(a[i], b[j], acc[i][j]);
            }
        }
    }

    float* sl = slab + (size_t)ky * 1280000;
#pragma unroll
    for (int h = 0; h < 2; ++h) {
        const int p  = h * 64 + pg * 4;
        const int py = y0 + (p >> 5);
        const int px = x0 + (p & 31);
        if (px >= 100) continue;
#pragma unroll
        for (int i = 0; i < 8; ++i) {
            float* dst = sl + (size_t)(og * 8 + i) * HW + py * WID + px;
            __builtin_memcpy(dst, &acc[i][h * 4], 16);
        }
    }
}

// ---------------------------------------------------------------------------
// bf16 MFMA implicit-GEMM conv (unchanged).
// ---------------------------------------------------------------------------
template<int CIN, int KS, int COUT, int EPI, bool ACT, int OPAD, int OPW, int KSPLIT>
__global__ __launch_bounds__(256)
void mfma_conv(const short* __restrict__ wpk, const short* __restrict__ xcl,
               const float* __restrict__ bias,
               float* __restrict__ outcm, short* __restrict__ outcl)
{
    constexpr int PW = 100 + 2 * (KS / 2);
    constexpr int CHUNK = (KS + KSPLIT - 1) / KSPLIT;
    const int lane = threadIdx.x & 63;
    const int wave = threadIdx.x >> 6;
    const int wr = wave >> 1;
    const int wc = wave & 1;
    const int lq = lane >> 4;
    const int ln = lane & 15;

    const int oc0 = blockIdx.x * 128;
    const int y0  = blockIdx.y * 4;
    const int zb  = blockIdx.z;
    const int bx  = (KSPLIT > 1) ? (zb & 3) : zb;
    const int ks  = (KSPLIT > 1) ? (zb >> 2) : 0;
    const int x0  = bx * 32;
    const int ky_lo = ks * CHUNK;
    const int ky_hi = (ky_lo + CHUNK < KS) ? ky_lo + CHUNK : KS;

    int bpix[4];
#pragma unroll
    for (int nt = 0; nt < 4; ++nt) {
        const int nl = wc * 64 + nt * 16 + ln;
        bpix[nt] = (y0 + (nl >> 5)) * PW + (x0 + (nl & 31));
    }

    f32x4 acc[4][4];
#pragma unroll
    for (int mt = 0; mt < 4; ++mt)
#pragma unroll
        for (int nt = 0; nt < 4; ++nt)
#pragma unroll
            for (int r = 0; r < 4; ++r) acc[mt][nt][r] = 0.f;

    const int arow0 = oc0 + wr * 64 + ln;

    for (int ky = ky_lo; ky < ky_hi; ++ky) {
#pragma unroll
        for (int kx = 0; kx < KS; ++kx) {
            const short* wsl = wpk + (size_t)((ky * KS + kx) * COUT) * CIN;
            const short* xsl = xcl + (size_t)(ky * PW + kx) * CIN;
            for (int ic0 = 0; ic0 < CIN; ic0 += 32) {
                bf16x8 a[4], b[4];
#pragma unroll
                for (int mt = 0; mt < 4; ++mt)
                    a[mt] = load_frag(wsl + (size_t)(arow0 + mt * 16) * CIN + ic0 + lq * 8);
#pragma unroll
                for (int nt = 0; nt < 4; ++nt)
                    b[nt] = load_frag(xsl + (size_t)bpix[nt] * CIN + ic0 + lq * 8);
#pragma unroll
                for (int mt = 0; mt < 4; ++mt)
#pragma unroll
                    for (int nt = 0; nt < 4; ++nt)
                        acc[mt][nt] = __builtin_amdgcn_mfma_f32_16x16x32_bf16(
                            a[mt], b[nt], acc[mt][nt], 0, 0, 0);
            }
        }
    }

#pragma unroll
    for (int mt = 0; mt < 4; ++mt) {
        const int ocr = oc0 + wr * 64 + mt * 16 + lq * 4;
        float bb[4];
        if (EPI == 1) {
            const float4 bv = *(const float4*)(bias + ocr);
            bb[0] = bv.x; bb[1] = bv.y; bb[2] = bv.z; bb[3] = bv.w;
        }
#pragma unroll
        for (int nt = 0; nt < 4; ++nt) {
            const int nl = wc * 64 + nt * 16 + ln;
            const int x = x0 + (nl & 31);
            const int y = y0 + (nl >> 5);
            if (x >= 100) continue;
            if (EPI == 1) {
                float v[4];
#pragma unroll
                for (int r = 0; r < 4; ++r) {
                    float t = acc[mt][nt][r] + bb[r];
                    if (ACT) t = gelu_exact(t);
                    v[r] = t;
                }
                ushort4 pk;
                pk.x = f2bf(v[0]); pk.y = f2bf(v[1]); pk.z = f2bf(v[2]); pk.w = f2bf(v[3]);
                *(ushort4*)(outcl + ((size_t)(y + OPAD) * OPW + (x + OPAD)) * COUT + ocr) = pk;
            } else {
                const int pix = y * WID + x;
#pragma unroll
                for (int r = 0; r < 4; ++r)
                    outcm[((size_t)ks * COUT + ocr + r) * HW + pix] = acc[mt][nt][r];
            }
        }
    }
}

// fused: out = inorm(bias + res + sum_z slab[z])
template<int NS>
__global__ __launch_bounds__(256)
void red_norm_k(const float* __restrict__ bias, const float* __restrict__ res,
                const float* __restrict__ slab, float* __restrict__ outp)
{
    const int c = blockIdx.x, tid = threadIdx.x;
    const size_t base = (size_t)c * HW;
    const float bc = bias[c];
    float v[40];
    float s1 = 0.f, s2 = 0.f;
#pragma unroll
    for (int k = 0; k < 40; ++k) {
        const int i = tid + k * 256;
        float x = 0.f;
        if (i < HW) {
            x = bc + res[base + i];
#pragma unroll
            for (int z = 0; z < NS; ++z) x += slab[(size_t)z * 1280000 + base + i];
            s1 += x; s2 += x * x;
        }
        v[k] = x;
    }
    __shared__ float r1[256], r2[256];
    r1[tid] = s1; r2[tid] = s2; __syncthreads();
    for (int o = 128; o > 0; o >>= 1) {
        if (tid < o) { r1[tid] += r1[tid + o]; r2[tid] += r2[tid + o]; }
        __syncthreads();
    }
    const float mean = r1[0] * 1e-4f;
    const float var  = fmaxf(r2[0] * 1e-4f - mean * mean, 0.f);
    const float rstd = rsqrtf(var + 1e-5f);
#pragma unroll
    for (int k = 0; k < 40; ++k) {
        const int i = tid + k * 256;
        if (i < HW) outp[base + i] = (v[k] - mean) * rstd;
    }
}

// fp32 channel-major [128][100][100] -> channel-major padded(2) [128][104][104]
__global__ void pad_xpad(const float* __restrict__ in, float* __restrict__ out)
{
    const int total = 128 * 104 * 104;
    for (int i = blockIdx.x * blockDim.x + threadIdx.x; i < total; i += gridDim.x * blockDim.x) {
        const int c = i / 10816;
        const int r = i % 10816;
        const int y = r / 104 - 2;
        const int x = r % 104 - 2;
        float v = 0.f;
        if (x >= 0 && x < 100 && y >= 0 && y < 100) v = in[(size_t)c * HW + y * WID + x];
        out[i] = v;
    }
}

template<int C, int PAD>
__global__ void pad_cl_cast(const float* __restrict__ in, short* __restrict__ out)
{
    constexpr int PW = 100 + 2 * PAD;
    const int total = PW * PW * C;
    for (int i = blockIdx.x * blockDim.x + threadIdx.x; i < total; i += gridDim.x * blockDim.x) {
        const int c = i % C;
        const int p = i / C;
        const int x = p % PW - PAD;
        const int y = p / PW - PAD;
        float v = 0.f;
        if (x >= 0 && x < 100 && y >= 0 && y < 100) v = in[(size_t)c * HW + y * WID + x];
        out[i] = (short)f2bf(v);
    }
}

__global__ void pack_all_bf16(const float* __restrict__ w1, const float* __restrict__ w2,
                              const float* __restrict__ w3, const float* __restrict__ w4,
                              short* __restrict__ out)
{
    const int E0 = 1179648, E1 = E0 + 262144, E2 = E1 + 589824, E3 = E2 + 409600;
    for (int i = blockIdx.x * blockDim.x + threadIdx.x; i < E3; i += gridDim.x * blockDim.x) {
        const float* w; int OC, CI, KS, j;
        if (i < E0)      { w = w1; OC = 512; CI = 256; KS = 3; j = i; }
        else if (i < E1) { w = w2; OC = 512; CI = 512; KS = 1; j = i - E0; }
        else if (i < E2) { w = w3; OC = 128; CI = 512; KS = 3; j = i - E1; }
        else             { w = w4; OC = 128; CI = 128; KS = 5; j = i - E2; }
        const int ic = j % CI;
        int t = j / CI;
        const int oc = t % OC;
        const int s = t / OC;
        const int ky = s / KS, kx = s % KS;
        out[i] = (short)f2bf(w[(((size_t)oc * CI + ic) * KS + ky) * KS + kx]);
    }
}

__global__ void pack_w1_f32(const float* __restrict__ w, float* __restrict__ out)
{
    const int total = 128 * 128 * 25;
    for (int i = blockIdx.x * blockDim.x + threadIdx.x; i < total; i += gridDim.x * blockDim.x) {
        const int oc = i % 128;
        int t = i / 128;
        const int ic = t % 128;
        const int s = t / 128;
        const int ky = s / 5, kx = s % 5;
        out[i] = w[(((size_t)oc * 128 + ic) * 5 + ky) * 5 + kx];
    }
}

// feature transposes -> bf16 channel-last, concatenated
__global__ void transpose_all(const float* __restrict__ f0, const float* __restrict__ f1,
                              const float* __restrict__ f2, const float* __restrict__ f3,
                              short* __restrict__ out)
{
    const int O1 = 2230272, O2 = O1 + 557568, O3 = O2 + 139392, O4 = O3 + 34848;
    for (int i = blockIdx.x * blockDim.x + threadIdx.x; i < O4; i += gridDim.x * blockDim.x) {
        const float* f; int Hl, Wl, j;
        if (i < O1)      { f = f0; Hl = 32; Wl = 88; j = i; }
        else if (i < O2) { f = f1; Hl = 16; Wl = 44; j = i - O1; }
        else if (i < O3) { f = f2; Hl = 8;  Wl = 22; j = i - O2; }
        else             { f = f3; Hl = 4;  Wl = 11; j = i - O3; }
        const int c = j % 132;
        int t = j / 132;
        const int x = t % Wl; t /= Wl;
        const int y = t % Hl; t /= Hl;
        const int n = t;
        out[i] = (short)f2bf(f[(((size_t)n * 132 + c) * Hl + y) * Wl + x]);
    }
}

// offsw + projection compaction fused (unchanged)
__global__ __launch_bounds__(64)
void offsw_proj(const float* __restrict__ qn, const float* __restrict__ bev_pos,
                const float* __restrict__ off_w, const float* __restrict__ off_b,
                const float* __restrict__ sw_w, const float* __restrict__ sw_b,
                const float* __restrict__ l2i,
                float* __restrict__ refp, float* __restrict__ swts,
                float2* __restrict__ recs, int* __restrict__ recn, int* __restrict__ cnts)
{
    const int pix = blockIdx.x;
    const int tid = threadIdx.x;
    __shared__ float qv[128];
    __shared__ float swraw[32];
    __shared__ float rp[24];
    qv[tid]      = qn[(size_t)tid * HW + pix];
    qv[tid + 64] = qn[(size_t)(tid + 64) * HW + pix];
    __syncthreads();

    if (tid < 24) {
        float acc = off_b[tid];
        for (int c = 0; c < 128; ++c) acc = fmaf(qv[c], off_w[tid * 128 + c], acc);
        const float s = 1.0f / (1.0f + expf(-acc));
        const int coord = tid % 3;
        const float rng = (coord < 2) ? 0.250001f : 4.000001f;
        const float v = s * rng * 2.0f - rng;
        const float lo[3]   = {-50.f, -50.f, -5.f};
        const float span[3] = {100.f, 100.f, 8.f};
        const float rv = bev_pos[pix * 3 + coord] * span[coord] + lo[coord] + v;
        refp[pix * 24 + tid] = rv;
        rp[tid] = rv;
    } else if (tid >= 32) {
        const int j = tid - 32;
        float acc = sw_b[j];
        for (int c = 0; c < 128; ++c) acc = fmaf(qv[c], sw_w[j * 128 + c], acc);
        swraw[j] = acc;
    }
    __syncthreads();
    if (tid < 8) {
        float m = -1e30f;
#pragma unroll
        for (int l = 0; l < 4; ++l) m = fmaxf(m, swraw[tid * 4 + l]);
        float e[4], sum = 0.f;
#pragma unroll
        for (int l = 0; l < 4; ++l) { e[l] = expf(swraw[tid * 4 + l] - m); sum += e[l]; }
        const float inv = 1.0f / sum;
#pragma unroll
        for (int l = 0; l < 4; ++l) swts[pix * 32 + tid * 4 + l] = e[l] * inv;
    }

    bool keep = false;
    float gx = -2.f, gy = -2.f;
    int p = 0, n = 0;
    if (tid < 48) {
        p = tid / 6;
        n = tid - p * 6;
        const float X = rp[p * 3 + 0], Y = rp[p * 3 + 1], Z = rp[p * 3 + 2];
        const float* m = l2i + n * 16;
        const float cx = m[0] * X + m[1] * Y + m[2]  * Z + m[3];
        const float cy = m[4] * X + m[5] * Y + m[6]  * Z + m[7];
        const float cz = m[8] * X + m[9] * Y + m[10] * Z + m[11];
        const bool valid = cz > 1e-5f;
        const float zz = fmaxf(cz, 1e-5f);
        gx = valid ? (cx / zz) * (2.0f / 704.0f) - 1.0f : -2.0f;
        gy = valid ? (cy / zz) * (2.0f / 256.0f) - 1.0f : -2.0f;
        keep = (gx > -1.092f) && (gx < 1.092f) && (gy > -1.26f) && (gy < 1.26f);
    }
    const unsigned long long bm = __ballot(keep);
    if (keep) {
        const unsigned long long gmask = 0x3Full << (p * 6);
        const int slot = __popcll(bm & ((1ull << tid) - 1ull) & gmask);
        recs[(size_t)pix * 48 + p * 6 + slot] = make_float2(gx, gy);
        recn[(size_t)pix * 48 + p * 6 + slot] = n;
    }
    if (tid < 48 && (tid % 6) == 0) {
        const unsigned long long gmask = 0x3Full << (p * 6);
        cnts[pix * 8 + p] = __popcll(bm & gmask);
    }
}

// ---------------------------------------------------------------------------
// sample_k4: one wave per pixel; lane = 2 adjacent channels (ushort2 loads,
// exact packed bf16->f32); tap offsets readfirstlane'd (saddr gathers).
// ---------------------------------------------------------------------------
__global__ __launch_bounds__(64)
void sample_k4(const float* __restrict__ refp, const float* __restrict__ swts,
               const float2* __restrict__ recs, const int* __restrict__ recn,
               const int* __restrict__ cnts,
               const short* __restrict__ fb0,   // concatenated bf16 feats
               short* __restrict__ sfo)
{
    const int pix = blockIdx.x;
    const int tid = threadIdx.x;                   // 64
    const int c0  = tid * 2;                       // channels c0, c0+1
    __shared__ float rp[24], sw[32], tail[32];
    __shared__ float2 rec[48];
    __shared__ int rn[48];
    __shared__ int cnt[8];
    __shared__ int4   toff[192];
    __shared__ float4 twt[192];
    if (tid < 24) rp[tid] = refp[pix * 24 + tid];
    if (tid < 32) sw[tid] = swts[pix * 32 + tid];
    if (tid < 48) { rec[tid] = recs[(size_t)pix * 48 + tid]; rn[tid] = recn[(size_t)pix * 48 + tid]; }
    if (tid < 8)  cnt[tid] = cnts[pix * 8 + tid];
    __syncthreads();

    const int HL[4] = {32, 16, 8, 4};
    const int WL[4] = {88, 44, 22, 11};
    const int LB[4] = {0, 2230272, 2787840, 2927232};   // level bases (shorts)

    // ---- phase 1: tap descriptors, one entry per (p, rec, level) ----
    for (int e = tid; e < 192; e += 64) {
        const int p  = e / 24;
        const int rl = e - p * 24;
        const int r  = rl >> 2;
        const int l  = rl & 3;
        int4 off = make_int4(0, 0, 0, 0);
        float4 wt = make_float4(0.f, 0.f, 0.f, 0.f);
        if (r < cnt[p]) {
            const float gx = rec[p * 6 + r].x;
            const float gy = rec[p * 6 + r].y;
            const int   n  = rn[p * 6 + r];
            const float wl = sw[p * 4 + l];
            const int Hl = HL[l], Wl = WL[l];
            const float fx = (gx + 1.0f) * 0.5f * (float)Wl - 0.5f;
            const float fy = (gy + 1.0f) * 0.5f * (float)Hl - 0.5f;
            if (fx >= -1.0f && fx < (float)Wl && fy >= -1.0f && fy < (float)Hl) {
                const float x0f = floorf(fx), y0f = floorf(fy);
                const int x0 = (int)x0f, y0 = (int)y0f;
                const int x1 = x0 + 1, y1 = y0 + 1;
                const float wx1 = fx - x0f, wy1 = fy - y0f;
                const float wx0 = 1.0f - wx1, wy0 = 1.0f - wy1;
                const bool okx0 = (x0 >= 0), okx1 = (x1 < Wl);
                const bool oky0 = (y0 >= 0), oky1 = (y1 < Hl);
                const int xc0 = okx0 ? x0 : 0, xc1 = okx1 ? x1 : Wl - 1;
                const int yc0 = oky0 ? y0 : 0, yc1 = oky1 ? y1 : Hl - 1;
                const int base = LB[l] + n * Hl * Wl * 132;
                off.x = base + (yc0 * Wl + xc0) * 132;
                off.y = base + (yc0 * Wl + xc1) * 132;
                off.z = base + (yc1 * Wl + xc0) * 132;
                off.w = base + (yc1 * Wl + xc1) * 132;
                wt.x = (okx0 && oky0) ? wx0 * wy0 * wl : 0.f;
                wt.y = (okx1 && oky0) ? wx1 * wy0 * wl : 0.f;
                wt.z = (okx0 && oky1) ? wx0 * wy1 * wl : 0.f;
                wt.w = (okx1 && oky1) ? wx1 * wy1 * wl : 0.f;
            }
        }
        toff[e] = off;
        twt[e]  = wt;
    }
    __syncthreads();

    // ---- phase 2: packed gather + FMA (lane = 2 channels) ----
    float2 acc[8], accT[8];
#pragma unroll
    for (int p = 0; p < 8; ++p) {
        float2 a0 = {0.f, 0.f}, a1 = {0.f, 0.f}, a2 = {0.f, 0.f}, a3 = {0.f, 0.f};
        float2 b0 = {0.f, 0.f}, b1 = {0.f, 0.f}, b2 = {0.f, 0.f}, b3 = {0.f, 0.f};
        const int c = cnt[p];
        for (int r = 0; r < c; ++r) {
            const int eb = p * 24 + r * 4;
#pragma unroll
            for (int l = 0; l < 4; ++l) {
                const int4   offv = toff[eb + l];
                const float4 wt   = twt[eb + l];
                const int ox = __builtin_amdgcn_readfirstlane(offv.x);
                const int oy = __builtin_amdgcn_readfirstlane(offv.y);
                const int oz = __builtin_amdgcn_readfirstlane(offv.z);
                const int ow = __builtin_amdgcn_readfirstlane(offv.w);
                const unsigned int ux = *(const unsigned int*)(fb0 + ox + c0);
                const unsigned int uy = *(const unsigned int*)(fb0 + oy + c0);
                const unsigned int uz = *(const unsigned int*)(fb0 + oz + c0);
                const unsigned int uw = *(const unsigned int*)(fb0 + ow + c0);
                a0.x = fmaf(__uint_as_float(ux << 16), wt.x, a0.x);
                a0.y = fmaf(__uint_as_float(ux & 0xFFFF0000u), wt.x, a0.y);
                a1.x = fmaf(__uint_as_float(uy << 16), wt.y, a1.x);
                a1.y = fmaf(__uint_as_float(uy & 0xFFFF0000u), wt.y, a1.y);
                a2.x = fmaf(__uint_as_float(uz << 16), wt.z, a2.x);
                a2.y = fmaf(__uint_as_float(uz & 0xFFFF0000u), wt.z, a2.y);
                a3.x = fmaf(__uint_as_float(uw << 16), wt.w, a3.x);
                a3.y = fmaf(__uint_as_float(uw & 0xFFFF0000u), wt.w, a3.y);
                if (tid < 2) {
                    const unsigned int vx = *(const unsigned int*)(fb0 + ox + 128 + c0);
                    const unsigned int vy = *(const unsigned int*)(fb0 + oy + 128 + c0);
                    const unsigned int vz = *(const unsigned int*)(fb0 + oz + 128 + c0);
                    const unsigned int vw = *(const unsigned int*)(fb0 + ow + 128 + c0);
                    b0.x = fmaf(__uint_as_float(vx << 16), wt.x, b0.x);
                    b0.y = fmaf(__uint_as_float(vx & 0xFFFF0000u), wt.x, b0.y);
                    b1.x = fmaf(__uint_as_float(vy << 16), wt.y, b1.x);
                    b1.y = fmaf(__uint_as_float(vy & 0xFFFF0000u), wt.y, b1.y);
                    b2.x = fmaf(__uint_as_float(vz << 16), wt.z, b2.x);
                    b2.y = fmaf(__uint_as_float(vz & 0xFFFF0000u), wt.z, b2.y);
                    b3.x = fmaf(__uint_as_float(vw << 16), wt.w, b3.x);
                    b3.y = fmaf(__uint_as_float(vw & 0xFFFF0000u), wt.w, b3.y);
                }
            }
        }
        acc[p].x  = (a0.x + a1.x) + (a2.x + a3.x);
        acc[p].y  = (a0.y + a1.y) + (a2.y + a3.y);
        accT[p].x = (b0.x + b1.x) + (b2.x + b3.x);
        accT[p].y = (b0.y + b1.y) + (b2.y + b3.y);
    }

    if (tid < 2) {
#pragma unroll
        for (int p = 0; p < 8; ++p) {
            tail[p * 4 + c0]     = accT[p].x;
            tail[p * 4 + c0 + 1] = accT[p].y;
        }
    }
    __syncthreads();

    float2 sf1 = {0.f, 0.f}, sf2 = {0.f, 0.f};
#pragma unroll
    for (int p = 0; p < 8; ++p) {
        const float dx = rp[p * 3]     - tail[p * 4 + 0];
        const float dy = rp[p * 3 + 1] - tail[p * 4 + 1];
        const float dz = rp[p * 3 + 2] - tail[p * 4 + 2];
        const float wgt = expf(-0.1f * (dx * dx + dy * dy + dz * dz));
        sf1.x += acc[p].x;  sf1.y += acc[p].y;
        sf2.x += acc[p].x * wgt;  sf2.y += acc[p].y * wgt;
    }
    const int y = pix / WID, x = pix % WID;
    const size_t po = ((size_t)(y + 1) * 102 + (x + 1)) * 256;
    ushort2 p1; p1.x = f2bf(sf1.x); p1.y = f2bf(sf1.y);
    ushort2 p2; p2.x = f2bf(sf2.x); p2.y = f2bf(sf2.y);
    *(ushort2*)(sfo + po + c0)       = p1;
    *(ushort2*)(sfo + po + 128 + c0) = p2;
}

// ---------------------------------------------------------------------------

extern "C" void kernel_launch(void* const* d_in, const int* in_sizes, int n_in,
                              void* d_out, int out_size, void* d_ws, size_t ws_size,
                              hipStream_t stream)
{
    const float* bev_query = (const float*)d_in[0];
    const float* bev_pos   = (const float*)d_in[1];
    const float* l2i       = (const float*)d_in[2];
    const float* feat0     = (const float*)d_in[3];
    const float* feat1     = (const float*)d_in[4];
    const float* feat2     = (const float*)d_in[5];
    const float* feat3     = (const float*)d_in[6];
    const float* in_w      = (const float*)d_in[7];
    const float* in_b      = (const float*)d_in[8];
    const float* off_w     = (const float*)d_in[9];
    const float* off_b     = (const float*)d_in[10];
    const float* sw_w      = (const float*)d_in[11];
    const float* sw_b      = (const float*)d_in[12];
    const float* mid_w1    = (const float*)d_in[13];
    const float* mid_b1    = (const float*)d_in[14];
    const float* mid_w2    = (const float*)d_in[15];
    const float* mid_b2    = (const float*)d_in[16];
    const float* mid_w3    = (const float*)d_in[17];
    const float* mid_b3    = (const float*)d_in[18];
    const float* out_w     = (const float*)d_in[19];
    const float* out_b     = (const float*)d_in[20];
    float* out = (float*)d_out;

    // ---- workspace layout (lifetime-aliased) ----
    float* ws    = (float*)d_ws;
    float* qn    = ws;                       // 1,280,000
    float* refp  = qn + 1280000;             //   240,000
    float* swts  = refp + 240000;            //   320,000
    float* E     = swts + 320000;            // 6,400,000 (slab5 | fTb+recs | m1_cl | slab3)
    float* F     = E + 6400000;              // 1,800,000 (xpadP+wpk1f | sf_cl | q2pad)
    float* H     = F + 1800000;              // 2,700,000 (m2_cl)
    short* wp_all= (short*)(H + 2700000);    // 2,441,216 sh

    float*  slab  = E;                       // conv1: 5 slabs; later convs: 3 slabs
    short*  fT0   = (short*)E;               // 2,962,080 shorts (bf16 feats, concatenated)
    float2* recs  = (float2*)(E + 1600000);  // 480,000 f2
    int*    recn  = (int*)(E + 2560000);     // 480,000
    int*    cnts  = (int*)(E + 3040000);     //  80,000
    short*  m1_cl = (short*)E;               // 5,120,000 sh [100][100][512]
    float*  xpadP = F;                       // 1,384,448 f
    float*  wpk1f = F + 1384448;             //   409,600 f
    short*  sf_cl = (short*)F;               // 2,663,424 sh [102][102][256]
    short*  q2pad = (short*)F;               // 1,384,448 sh [104][104][128]
    short*  m2_cl = (short*)H;               // 5,326,848 sh [102][102][512]
    short*  wp_m1 = wp_all;                  // 1,179,648
    short*  wp_m2 = wp_m1 + 1179648;         //   262,144
    short*  wp_m3 = wp_m2 + 262144;          //   589,824
    short*  wp_out= wp_m3 + 589824;          //   409,600

    const dim3 blk(256);

    // ---- weight packing ----
    hipLaunchKernelGGL(pack_w1_f32, dim3(1600), blk, 0, stream, in_w, wpk1f);
    hipLaunchKernelGGL(pack_all_bf16, dim3(9536), blk, 0, stream,
                       mid_w1, mid_w2, mid_w3, out_w, wp_all);

    // ---- 1. q1 slabs = conv5x5_f32(bev_query), then qn = inorm(q1) fused ----
    hipLaunchKernelGGL(pad_xpad, dim3(5408), blk, 0, stream, bev_query, xpadP);
    hipLaunchKernelGGL(conv1_f32, dim3(4, 25, 5), blk, 0, stream, wpk1f, xpadP, slab);
    hipLaunchKernelGGL(red_norm_k<5>, dim3(128), blk, 0, stream, in_b, bev_query, slab, qn);

    // ---- 2. ref points + softmax weights + projection compaction ----
    hipLaunchKernelGGL(offsw_proj, dim3(HW), dim3(64), 0, stream,
                       qn, bev_pos, off_w, off_b, sw_w, sw_b, l2i,
                       refp, swts, recs, recn, cnts);

    // ---- 3. feature transposes -> bf16 (slab5 dead) ----
    hipLaunchKernelGGL(transpose_all, dim3(11571), blk, 0, stream,
                       feat0, feat1, feat2, feat3, fT0);

    // ---- 4. sampling -> sf_cl bf16 padded(1) ----
    hipMemsetAsync(sf_cl, 0, (size_t)2663424 * 2, stream);
    hipLaunchKernelGGL(sample_k4, dim3(HW), dim3(64), 0, stream,
                       refp, swts, recs, recn, cnts, fT0, sf_cl);

    // ---- 5. m1 = gelu(conv3x3 256->512) ----
    hipLaunchKernelGGL((mfma_conv<256, 3, 512, 1, true, 0, 100, 1>), dim3(4, 25, 4), blk, 0, stream,
                       wp_m1, sf_cl, mid_b1, nullptr, m1_cl);
    // ---- 6. m2 = gelu(conv1x1 512->512) -> padded(1) ----
    hipMemsetAsync(m2_cl, 0, (size_t)5326848 * 2, stream);
    hipLaunchKernelGGL((mfma_conv<512, 1, 512, 1, true, 1, 102, 1>), dim3(4, 25, 4), blk, 0, stream,
                       wp_m2, m1_cl, mid_b2, nullptr, m2_cl);
    // ---- 7. q2 = inorm(qn + conv3x3 512->128) ----
    hipLaunchKernelGGL((mfma_conv<512, 3, 128, 2, false, 0, 0, 3>), dim3(1, 25, 12), blk, 0, stream,
                       wp_m3, m2_cl, mid_b3, slab, nullptr);
    hipLaunchKernelGGL(red_norm_k<3>, dim3(128), blk, 0, stream, mid_b3, qn, slab, qn);
    // ---- 8. q3 = inorm(qn + conv5x5 bf16) ----
    hipLaunchKernelGGL((pad_cl_cast<128, 2>), dim3(5411), blk, 0, stream, qn, q2pad);
    hipLaunchKernelGGL((mfma_conv<128, 5, 128, 2, false, 0, 0, 3>), dim3(1, 25, 12), blk, 0, stream,
                       wp_out, q2pad, out_b, slab, nullptr);
    hipLaunchKernelGGL(red_norm_k<3>, dim3(128), blk, 0, stream, out_b, qn, slab, out);
}

// Round 12
// 783.665 us; speedup vs baseline: 1.1025x; 1.0007x over previous
//
#include <hip/hip_runtime.h>
#include <cstddef>

// ---------------------------------------------------------------------------
// SegTransformerDecoder — round 12 (round 11 + conv1_f32 v5).
//  * conv1_f32 v5: grid (4,50,5)=1000 blocks (2 rows/block, 128oc x 64pix,
//    thread 8oc x 4pix) — doubles blocks/CU at identical FMA order and
//    conflict-free LDS patterns. Bit-identical output to round 11.
// ---------------------------------------------------------------------------

#define HW   10000
#define WID  100

typedef __attribute__((ext_vector_type(8))) __bf16 bf16x8;
typedef __attribute__((ext_vector_type(4))) float f32x4;
typedef __attribute__((ext_vector_type(4))) unsigned int uint4v;

__device__ __forceinline__ float gelu_exact(float x) {
    return 0.5f * x * (1.0f + erff(x * 0.7071067811865475f));
}
__device__ __forceinline__ unsigned short f2bf(float v) {
    unsigned int b = __float_as_uint(v);
    return (unsigned short)((b + 0x7FFFu + ((b >> 16) & 1u)) >> 16);
}
__device__ __forceinline__ float bf2f(short s) {
    return __uint_as_float(((unsigned int)(unsigned short)s) << 16);
}
__device__ __forceinline__ bf16x8 load_frag(const short* p) {
    return __builtin_bit_cast(bf16x8, *(const uint4v*)p);
}

// ---------------------------------------------------------------------------
// conv1_f32 v5 (decision chain, exact fp32; FMA order identical to v4).
// input xpadP: channel-major padded(2) [128][104][104] fp32
// weights wpkf: [ky][kx][ic][oc] fp32
// block 256 thr, tile 128oc x 64pix (2 rows x 32 cols); thread = 8oc x 4pix.
// grid (4, 50, 5); z = ky; slab[z][oc][pix] store.
// ---------------------------------------------------------------------------
__global__ __launch_bounds__(256)
void conv1_f32(const float* __restrict__ wpkf, const float* __restrict__ xpadP,
               float* __restrict__ slab)
{
    __shared__ float As[2048];      // [ic 16][oc 128]
    __shared__ float Bs[1024];      // [ic 16][pix 64]
    const int t  = threadIdx.x;
    const int og = t >> 4;          // 16 groups of 8 oc
    const int pg = t & 15;          // 16 groups of 4 pix
    const int x0 = blockIdx.x * 32, y0 = blockIdx.y * 2;
    const int ky = blockIdx.z;

    // As staging: 2048 floats (2 x float4 per thread, contiguous)
    const int e0 = t * 4, e1 = 1024 + t * 4;
    // Bs staging: 1024 floats (1 x float4 per thread): ic = t>>4, p = (t*4)&63
    const int icB  = t >> 4;
    const int pB   = (t * 4) & 63;
    const int rowB = (y0 + (pB >> 5) + ky) * 104 + x0 + (pB & 31);

    float acc[8][4];
#pragma unroll
    for (int i = 0; i < 8; ++i)
#pragma unroll
        for (int j = 0; j < 4; ++j) acc[i][j] = 0.f;

    for (int kx = 0; kx < 5; ++kx) {
        for (int ic0 = 0; ic0 < 128; ic0 += 16) {
            __syncthreads();
            const float* asrc = wpkf + (size_t)((ky * 5 + kx) * 128 + ic0) * 128;
            *(float4*)(As + e0) = *(const float4*)(asrc + e0);
            *(float4*)(As + e1) = *(const float4*)(asrc + e1);
            float4 bv;
            __builtin_memcpy(&bv, xpadP + (size_t)(ic0 + icB) * 10816 + rowB + kx, 16);
            *(float4*)(Bs + t * 4) = bv;
            __syncthreads();
#pragma unroll
            for (int k = 0; k < 16; ++k) {
                float a[8], b[4];
                *(float4*)(a)     = *(float4*)(As + k * 128 + og * 8);
                *(float4*)(a + 4) = *(float4*)(As + k * 128 + og * 8 + 4);
                *(float4*)(b)     = *(float4*)(Bs + k * 64 + pg * 4);
#pragma unroll
                for (int i = 0; i < 8; ++i)
#pragma unroll
                    for (int j = 0; j < 4; ++j)
                        acc[i][j] = fmaf(a[i], b[j], acc[i][j]);
            }
        }
    }

    // epilogue: one 4-pixel run per thread, float4 stores
    float* sl = slab + (size_t)ky * 1280000;
    const int p  = pg * 4;
    const int py = y0 + (p >> 5);
    const int px = x0 + (p & 31);
    if (px < 100) {
#pragma unroll
        for (int i = 0; i < 8; ++i) {
            float* dst = sl + (size_t)(og * 8 + i) * HW + py * WID + px;
            __builtin_memcpy(dst, &acc[i][0], 16);
        }
    }
}

// ---------------------------------------------------------------------------
// bf16 MFMA implicit-GEMM conv (unchanged).
// ---------------------------------------------------------------------------
template<int CIN, int KS, int COUT, int EPI, bool ACT, int OPAD, int OPW, int KSPLIT>
__global__ __launch_bounds__(256)
void mfma_conv(const short* __restrict__ wpk, const short* __restrict__ xcl,
               const float* __restrict__ bias,
               float* __restrict__ outcm, short* __restrict__ outcl)
{
    constexpr int PW = 100 + 2 * (KS / 2);
    constexpr int CHUNK = (KS + KSPLIT - 1) / KSPLIT;
    const int lane = threadIdx.x & 63;
    const int wave = threadIdx.x >> 6;
    const int wr = wave >> 1;
    const int wc = wave & 1;
    const int lq = lane >> 4;
    const int ln = lane & 15;

    const int oc0 = blockIdx.x * 128;
    const int y0  = blockIdx.y * 4;
    const int zb  = blockIdx.z;
    const int bx  = (KSPLIT > 1) ? (zb & 3) : zb;
    const int ks  = (KSPLIT > 1) ? (zb >> 2) : 0;
    const int x0  = bx * 32;
    const int ky_lo = ks * CHUNK;
    const int ky_hi = (ky_lo + CHUNK < KS) ? ky_lo + CHUNK : KS;

    int bpix[4];
#pragma unroll
    for (int nt = 0; nt < 4; ++nt) {
        const int nl = wc * 64 + nt * 16 + ln;
        bpix[nt] = (y0 + (nl >> 5)) * PW + (x0 + (nl & 31));
    }

    f32x4 acc[4][4];
#pragma unroll
    for (int mt = 0; mt < 4; ++mt)
#pragma unroll
        for (int nt = 0; nt < 4; ++nt)
#pragma unroll
            for (int r = 0; r < 4; ++r) acc[mt][nt][r] = 0.f;

    const int arow0 = oc0 + wr * 64 + ln;

    for (int ky = ky_lo; ky < ky_hi; ++ky) {
#pragma unroll
        for (int kx = 0; kx < KS; ++kx) {
            const short* wsl = wpk + (size_t)((ky * KS + kx) * COUT) * CIN;
            const short* xsl = xcl + (size_t)(ky * PW + kx) * CIN;
            for (int ic0 = 0; ic0 < CIN; ic0 += 32) {
                bf16x8 a[4], b[4];
#pragma unroll
                for (int mt = 0; mt < 4; ++mt)
                    a[mt] = load_frag(wsl + (size_t)(arow0 + mt * 16) * CIN + ic0 + lq * 8);
#pragma unroll
                for (int nt = 0; nt < 4; ++nt)
                    b[nt] = load_frag(xsl + (size_t)bpix[nt] * CIN + ic0 + lq * 8);
#pragma unroll
                for (int mt = 0; mt < 4; ++mt)
#pragma unroll
                    for (int nt = 0; nt < 4; ++nt)
                        acc[mt][nt] = __builtin_amdgcn_mfma_f32_16x16x32_bf16(
                            a[mt], b[nt], acc[mt][nt], 0, 0, 0);
            }
        }
    }

#pragma unroll
    for (int mt = 0; mt < 4; ++mt) {
        const int ocr = oc0 + wr * 64 + mt * 16 + lq * 4;
        float bb[4];
        if (EPI == 1) {
            const float4 bv = *(const float4*)(bias + ocr);
            bb[0] = bv.x; bb[1] = bv.y; bb[2] = bv.z; bb[3] = bv.w;
        }
#pragma unroll
        for (int nt = 0; nt < 4; ++nt) {
            const int nl = wc * 64 + nt * 16 + ln;
            const int x = x0 + (nl & 31);
            const int y = y0 + (nl >> 5);
            if (x >= 100) continue;
            if (EPI == 1) {
                float v[4];
#pragma unroll
                for (int r = 0; r < 4; ++r) {
                    float t = acc[mt][nt][r] + bb[r];
                    if (ACT) t = gelu_exact(t);
                    v[r] = t;
                }
                ushort4 pk;
                pk.x = f2bf(v[0]); pk.y = f2bf(v[1]); pk.z = f2bf(v[2]); pk.w = f2bf(v[3]);
                *(ushort4*)(outcl + ((size_t)(y + OPAD) * OPW + (x + OPAD)) * COUT + ocr) = pk;
            } else {
                const int pix = y * WID + x;
#pragma unroll
                for (int r = 0; r < 4; ++r)
                    outcm[((size_t)ks * COUT + ocr + r) * HW + pix] = acc[mt][nt][r];
            }
        }
    }
}

// fused: out = inorm(bias + res + sum_z slab[z])
template<int NS>
__global__ __launch_bounds__(256)
void red_norm_k(const float* __restrict__ bias, const float* __restrict__ res,
                const float* __restrict__ slab, float* __restrict__ outp)
{
    const int c = blockIdx.x, tid = threadIdx.x;
    const size_t base = (size_t)c * HW;
    const float bc = bias[c];
    float v[40];
    float s1 = 0.f, s2 = 0.f;
#pragma unroll
    for (int k = 0; k < 40; ++k) {
        const int i = tid + k * 256;
        float x = 0.f;
        if (i < HW) {
            x = bc + res[base + i];
#pragma unroll
            for (int z = 0; z < NS; ++z) x += slab[(size_t)z * 1280000 + base + i];
            s1 += x; s2 += x * x;
        }
        v[k] = x;
    }
    __shared__ float r1[256], r2[256];
    r1[tid] = s1; r2[tid] = s2; __syncthreads();
    for (int o = 128; o > 0; o >>= 1) {
        if (tid < o) { r1[tid] += r1[tid + o]; r2[tid] += r2[tid + o]; }
        __syncthreads();
    }
    const float mean = r1[0] * 1e-4f;
    const float var  = fmaxf(r2[0] * 1e-4f - mean * mean, 0.f);
    const float rstd = rsqrtf(var + 1e-5f);
#pragma unroll
    for (int k = 0; k < 40; ++k) {
        const int i = tid + k * 256;
        if (i < HW) outp[base + i] = (v[k] - mean) * rstd;
    }
}

// fp32 channel-major [128][100][100] -> channel-major padded(2) [128][104][104]
__global__ void pad_xpad(const float* __restrict__ in, float* __restrict__ out)
{
    const int total = 128 * 104 * 104;
    for (int i = blockIdx.x * blockDim.x + threadIdx.x; i < total; i += gridDim.x * blockDim.x) {
        const int c = i / 10816;
        const int r = i % 10816;
        const int y = r / 104 - 2;
        const int x = r % 104 - 2;
        float v = 0.f;
        if (x >= 0 && x < 100 && y >= 0 && y < 100) v = in[(size_t)c * HW + y * WID + x];
        out[i] = v;
    }
}

template<int C, int PAD>
__global__ void pad_cl_cast(const float* __restrict__ in, short* __restrict__ out)
{
    constexpr int PW = 100 + 2 * PAD;
    const int total = PW * PW * C;
    for (int i = blockIdx.x * blockDim.x + threadIdx.x; i < total; i += gridDim.x * blockDim.x) {
        const int c = i % C;
        const int p = i / C;
        const int x = p % PW - PAD;
        const int y = p / PW - PAD;
        float v = 0.f;
        if (x >= 0 && x < 100 && y >= 0 && y < 100) v = in[(size_t)c * HW + y * WID + x];
        out[i] = (short)f2bf(v);
    }
}

__global__ void pack_all_bf16(const float* __restrict__ w1, const float* __restrict__ w2,
                              const float* __restrict__ w3, const float* __restrict__ w4,
                              short* __restrict__ out)
{
    const int E0 = 1179648, E1 = E0 + 262144, E2 = E1 + 589824, E3 = E2 + 409600;
    for (int i = blockIdx.x * blockDim.x + threadIdx.x; i < E3; i += gridDim.x * blockDim.x) {
        const float* w; int OC, CI, KS, j;
        if (i < E0)      { w = w1; OC = 512; CI = 256; KS = 3; j = i; }
        else if (i < E1) { w = w2; OC = 512; CI = 512; KS = 1; j = i - E0; }
        else if (i < E2) { w = w3; OC = 128; CI = 512; KS = 3; j = i - E1; }
        else             { w = w4; OC = 128; CI = 128; KS = 5; j = i - E2; }
        const int ic = j % CI;
        int t = j / CI;
        const int oc = t % OC;
        const int s = t / OC;
        const int ky = s / KS, kx = s % KS;
        out[i] = (short)f2bf(w[(((size_t)oc * CI + ic) * KS + ky) * KS + kx]);
    }
}

__global__ void pack_w1_f32(const float* __restrict__ w, float* __restrict__ out)
{
    const int total = 128 * 128 * 25;
    for (int i = blockIdx.x * blockDim.x + threadIdx.x; i < total; i += gridDim.x * blockDim.x) {
        const int oc = i % 128;
        int t = i / 128;
        const int ic = t % 128;
        const int s = t / 128;
        const int ky = s / 5, kx = s % 5;
        out[i] = w[(((size_t)oc * 128 + ic) * 5 + ky) * 5 + kx];
    }
}

// feature transposes -> bf16 channel-last, concatenated
__global__ void transpose_all(const float* __restrict__ f0, const float* __restrict__ f1,
                              const float* __restrict__ f2, const float* __restrict__ f3,
                              short* __restrict__ out)
{
    const int O1 = 2230272, O2 = O1 + 557568, O3 = O2 + 139392, O4 = O3 + 34848;
    for (int i = blockIdx.x * blockDim.x + threadIdx.x; i < O4; i += gridDim.x * blockDim.x) {
        const float* f; int Hl, Wl, j;
        if (i < O1)      { f = f0; Hl = 32; Wl = 88; j = i; }
        else if (i < O2) { f = f1; Hl = 16; Wl = 44; j = i - O1; }
        else if (i < O3) { f = f2; Hl = 8;  Wl = 22; j = i - O2; }
        else             { f = f3; Hl = 4;  Wl = 11; j = i - O3; }
        const int c = j % 132;
        int t = j / 132;
        const int x = t % Wl; t /= Wl;
        const int y = t % Hl; t /= Hl;
        const int n = t;
        out[i] = (short)f2bf(f[(((size_t)n * 132 + c) * Hl + y) * Wl + x]);
    }
}

// offsw + projection compaction fused (unchanged)
__global__ __launch_bounds__(64)
void offsw_proj(const float* __restrict__ qn, const float* __restrict__ bev_pos,
                const float* __restrict__ off_w, const float* __restrict__ off_b,
                const float* __restrict__ sw_w, const float* __restrict__ sw_b,
                const float* __restrict__ l2i,
                float* __restrict__ refp, float* __restrict__ swts,
                float2* __restrict__ recs, int* __restrict__ recn, int* __restrict__ cnts)
{
    const int pix = blockIdx.x;
    const int tid = threadIdx.x;
    __shared__ float qv[128];
    __shared__ float swraw[32];
    __shared__ float rp[24];
    qv[tid]      = qn[(size_t)tid * HW + pix];
    qv[tid + 64] = qn[(size_t)(tid + 64) * HW + pix];
    __syncthreads();

    if (tid < 24) {
        float acc = off_b[tid];
        for (int c = 0; c < 128; ++c) acc = fmaf(qv[c], off_w[tid * 128 + c], acc);
        const float s = 1.0f / (1.0f + expf(-acc));
        const int coord = tid % 3;
        const float rng = (coord < 2) ? 0.250001f : 4.000001f;
        const float v = s * rng * 2.0f - rng;
        const float lo[3]   = {-50.f, -50.f, -5.f};
        const float span[3] = {100.f, 100.f, 8.f};
        const float rv = bev_pos[pix * 3 + coord] * span[coord] + lo[coord] + v;
        refp[pix * 24 + tid] = rv;
        rp[tid] = rv;
    } else if (tid >= 32) {
        const int j = tid - 32;
        float acc = sw_b[j];
        for (int c = 0; c < 128; ++c) acc = fmaf(qv[c], sw_w[j * 128 + c], acc);
        swraw[j] = acc;
    }
    __syncthreads();
    if (tid < 8) {
        float m = -1e30f;
#pragma unroll
        for (int l = 0; l < 4; ++l) m = fmaxf(m, swraw[tid * 4 + l]);
        float e[4], sum = 0.f;
#pragma unroll
        for (int l = 0; l < 4; ++l) { e[l] = expf(swraw[tid * 4 + l] - m); sum += e[l]; }
        const float inv = 1.0f / sum;
#pragma unroll
        for (int l = 0; l < 4; ++l) swts[pix * 32 + tid * 4 + l] = e[l] * inv;
    }

    bool keep = false;
    float gx = -2.f, gy = -2.f;
    int p = 0, n = 0;
    if (tid < 48) {
        p = tid / 6;
        n = tid - p * 6;
        const float X = rp[p * 3 + 0], Y = rp[p * 3 + 1], Z = rp[p * 3 + 2];
        const float* m = l2i + n * 16;
        const float cx = m[0] * X + m[1] * Y + m[2]  * Z + m[3];
        const float cy = m[4] * X + m[5] * Y + m[6]  * Z + m[7];
        const float cz = m[8] * X + m[9] * Y + m[10] * Z + m[11];
        const bool valid = cz > 1e-5f;
        const float zz = fmaxf(cz, 1e-5f);
        gx = valid ? (cx / zz) * (2.0f / 704.0f) - 1.0f : -2.0f;
        gy = valid ? (cy / zz) * (2.0f / 256.0f) - 1.0f : -2.0f;
        keep = (gx > -1.092f) && (gx < 1.092f) && (gy > -1.26f) && (gy < 1.26f);
    }
    const unsigned long long bm = __ballot(keep);
    if (keep) {
        const unsigned long long gmask = 0x3Full << (p * 6);
        const int slot = __popcll(bm & ((1ull << tid) - 1ull) & gmask);
        recs[(size_t)pix * 48 + p * 6 + slot] = make_float2(gx, gy);
        recn[(size_t)pix * 48 + p * 6 + slot] = n;
    }
    if (tid < 48 && (tid % 6) == 0) {
        const unsigned long long gmask = 0x3Full << (p * 6);
        cnts[pix * 8 + p] = __popcll(bm & gmask);
    }
}

// ---------------------------------------------------------------------------
// sample_k4 (unchanged from round 11).
// ---------------------------------------------------------------------------
__global__ __launch_bounds__(64)
void sample_k4(const float* __restrict__ refp, const float* __restrict__ swts,
               const float2* __restrict__ recs, const int* __restrict__ recn,
               const int* __restrict__ cnts,
               const short* __restrict__ fb0,   // concatenated bf16 feats
               short* __restrict__ sfo)
{
    const int pix = blockIdx.x;
    const int tid = threadIdx.x;                   // 64
    const int c0  = tid * 2;                       // channels c0, c0+1
    __shared__ float rp[24], sw[32], tail[32];
    __shared__ float2 rec[48];
    __shared__ int rn[48];
    __shared__ int cnt[8];
    __shared__ int4   toff[192];
    __shared__ float4 twt[192];
    if (tid < 24) rp[tid] = refp[pix * 24 + tid];
    if (tid < 32) sw[tid] = swts[pix * 32 + tid];
    if (tid < 48) { rec[tid] = recs[(size_t)pix * 48 + tid]; rn[tid] = recn[(size_t)pix * 48 + tid]; }
    if (tid < 8)  cnt[tid] = cnts[pix * 8 + tid];
    __syncthreads();

    const int HL[4] = {32, 16, 8, 4};
    const int WL[4] = {88, 44, 22, 11};
    const int LB[4] = {0, 2230272, 2787840, 2927232};   // level bases (shorts)

    for (int e = tid; e < 192; e += 64) {
        const int p  = e / 24;
        const int rl = e - p * 24;
        const int r  = rl >> 2;
        const int l  = rl & 3;
        int4 off = make_int4(0, 0, 0, 0);
        float4 wt = make_float4(0.f, 0.f, 0.f, 0.f);
        if (r < cnt[p]) {
            const float gx = rec[p * 6 + r].x;
            const float gy = rec[p * 6 + r].y;
            const int   n  = rn[p * 6 + r];
            const float wl = sw[p * 4 + l];
            const int Hl = HL[l], Wl = WL[l];
            const float fx = (gx + 1.0f) * 0.5f * (float)Wl - 0.5f;
            const float fy = (gy + 1.0f) * 0.5f * (float)Hl - 0.5f;
            if (fx >= -1.0f && fx < (float)Wl && fy >= -1.0f && fy < (float)Hl) {
                const float x0f = floorf(fx), y0f = floorf(fy);
                const int x0 = (int)x0f, y0 = (int)y0f;
                const int x1 = x0 + 1, y1 = y0 + 1;
                const float wx1 = fx - x0f, wy1 = fy - y0f;
                const float wx0 = 1.0f - wx1, wy0 = 1.0f - wy1;
                const bool okx0 = (x0 >= 0), okx1 = (x1 < Wl);
                const bool oky0 = (y0 >= 0), oky1 = (y1 < Hl);
                const int xc0 = okx0 ? x0 : 0, xc1 = okx1 ? x1 : Wl - 1;
                const int yc0 = oky0 ? y0 : 0, yc1 = oky1 ? y1 : Hl - 1;
                const int base = LB[l] + n * Hl * Wl * 132;
                off.x = base + (yc0 * Wl + xc0) * 132;
                off.y = base + (yc0 * Wl + xc1) * 132;
                off.z = base + (yc1 * Wl + xc0) * 132;
                off.w = base + (yc1 * Wl + xc1) * 132;
                wt.x = (okx0 && oky0) ? wx0 * wy0 * wl : 0.f;
                wt.y = (okx1 && oky0) ? wx1 * wy0 * wl : 0.f;
                wt.z = (okx0 && oky1) ? wx0 * wy1 * wl : 0.f;
                wt.w = (okx1 && oky1) ? wx1 * wy1 * wl : 0.f;
            }
        }
        toff[e] = off;
        twt[e]  = wt;
    }
    __syncthreads();

    float2 acc[8], accT[8];
#pragma unroll
    for (int p = 0; p < 8; ++p) {
        float2 a0 = {0.f, 0.f}, a1 = {0.f, 0.f}, a2 = {0.f, 0.f}, a3 = {0.f, 0.f};
        float2 b0 = {0.f, 0.f}, b1 = {0.f, 0.f}, b2 = {0.f, 0.f}, b3 = {0.f, 0.f};
        const int c = cnt[p];
        for (int r = 0; r < c; ++r) {
            const int eb = p * 24 + r * 4;
#pragma unroll
            for (int l = 0; l < 4; ++l) {
                const int4   offv = toff[eb + l];
                const float4 wt   = twt[eb + l];
                const int ox = __builtin_amdgcn_readfirstlane(offv.x);
                const int oy = __builtin_amdgcn_readfirstlane(offv.y);
                const int oz = __builtin_amdgcn_readfirstlane(offv.z);
                const int ow = __builtin_amdgcn_readfirstlane(offv.w);
                const unsigned int ux = *(const unsigned int*)(fb0 + ox + c0);
                const unsigned int uy = *(const unsigned int*)(fb0 + oy + c0);
                const unsigned int uz = *(const unsigned int*)(fb0 + oz + c0);
                const unsigned int uw = *(const unsigned int*)(fb0 + ow + c0);
                a0.x = fmaf(__uint_as_float(ux << 16), wt.x, a0.x);
                a0.y = fmaf(__uint_as_float(ux & 0xFFFF0000u), wt.x, a0.y);
                a1.x = fmaf(__uint_as_float(uy << 16), wt.y, a1.x);
                a1.y = fmaf(__uint_as_float(uy & 0xFFFF0000u), wt.y, a1.y);
                a2.x = fmaf(__uint_as_float(uz << 16), wt.z, a2.x);
                a2.y = fmaf(__uint_as_float(uz & 0xFFFF0000u), wt.z, a2.y);
                a3.x = fmaf(__uint_as_float(uw << 16), wt.w, a3.x);
                a3.y = fmaf(__uint_as_float(uw & 0xFFFF0000u), wt.w, a3.y);
                if (tid < 2) {
                    const unsigned int vx = *(const unsigned int*)(fb0 + ox + 128 + c0);
                    const unsigned int vy = *(const unsigned int*)(fb0 + oy + 128 + c0);
                    const unsigned int vz = *(const unsigned int*)(fb0 + oz + 128 + c0);
                    const unsigned int vw = *(const unsigned int*)(fb0 + ow + 128 + c0);
                    b0.x = fmaf(__uint_as_float(vx << 16), wt.x, b0.x);
                    b0.y = fmaf(__uint_as_float(vx & 0xFFFF0000u), wt.x, b0.y);
                    b1.x = fmaf(__uint_as_float(vy << 16), wt.y, b1.x);
                    b1.y = fmaf(__uint_as_float(vy & 0xFFFF0000u), wt.y, b1.y);
                    b2.x = fmaf(__uint_as_float(vz << 16), wt.z, b2.x);
                    b2.y = fmaf(__uint_as_float(vz & 0xFFFF0000u), wt.z, b2.y);
                    b3.x = fmaf(__uint_as_float(vw << 16), wt.w, b3.x);
                    b3.y = fmaf(__uint_as_float(vw & 0xFFFF0000u), wt.w, b3.y);
                }
            }
        }
        acc[p].x  = (a0.x + a1.x) + (a2.x + a3.x);
        acc[p].y  = (a0.y + a1.y) + (a2.y + a3.y);
        accT[p].x = (b0.x + b1.x) + (b2.x + b3.x);
        accT[p].y = (b0.y + b1.y) + (b2.y + b3.y);
    }

    if (tid < 2) {
#pragma unroll
        for (int p = 0; p < 8; ++p) {
            tail[p * 4 + c0]     = accT[p].x;
            tail[p * 4 + c0 + 1] = accT[p].y;
        }
    }
    __syncthreads();

    float2 sf1 = {0.f, 0.f}, sf2 = {0.f, 0.f};
#pragma unroll
    for (int p = 0; p < 8; ++p) {
        const float dx = rp[p * 3]     - tail[p * 4 + 0];
        const float dy = rp[p * 3 + 1] - tail[p * 4 + 1];
        const float dz = rp[p * 3 + 2] - tail[p * 4 + 2];
        const float wgt = expf(-0.1f * (dx * dx + dy * dy + dz * dz));
        sf1.x += acc[p].x;  sf1.y += acc[p].y;
        sf2.x += acc[p].x * wgt;  sf2.y += acc[p].y * wgt;
    }
    const int y = pix / WID, x = pix % WID;
    const size_t po = ((size_t)(y + 1) * 102 + (x + 1)) * 256;
    ushort2 p1; p1.x = f2bf(sf1.x); p1.y = f2bf(sf1.y);
    ushort2 p2; p2.x = f2bf(sf2.x); p2.y = f2bf(sf2.y);
    *(ushort2*)(sfo + po + c0)       = p1;
    *(ushort2*)(sfo + po + 128 + c0) = p2;
}

// ---------------------------------------------------------------------------

extern "C" void kernel_launch(void* const* d_in, const int* in_sizes, int n_in,
                              void* d_out, int out_size, void* d_ws, size_t ws_size,
                              hipStream_t stream)
{
    const float* bev_query = (const float*)d_in[0];
    const float* bev_pos   = (const float*)d_in[1];
    const float* l2i       = (const float*)d_in[2];
    const float* feat0     = (const float*)d_in[3];
    const float* feat1     = (const float*)d_in[4];
    const float* feat2     = (const float*)d_in[5];
    const float* feat3     = (const float*)d_in[6];
    const float* in_w      = (const float*)d_in[7];
    const float* in_b      = (const float*)d_in[8];
    const float* off_w     = (const float*)d_in[9];
    const float* off_b     = (const float*)d_in[10];
    const float* sw_w      = (const float*)d_in[11];
    const float* sw_b      = (const float*)d_in[12];
    const float* mid_w1    = (const float*)d_in[13];
    const float* mid_b1    = (const float*)d_in[14];
    const float* mid_w2    = (const float*)d_in[15];
    const float* mid_b2    = (const float*)d_in[16];
    const float* mid_w3    = (const float*)d_in[17];
    const float* mid_b3    = (const float*)d_in[18];
    const float* out_w     = (const float*)d_in[19];
    const float* out_b     = (const float*)d_in[20];
    float* out = (float*)d_out;

    // ---- workspace layout (lifetime-aliased) ----
    float* ws    = (float*)d_ws;
    float* qn    = ws;                       // 1,280,000
    float* refp  = qn + 1280000;             //   240,000
    float* swts  = refp + 240000;            //   320,000
    float* E     = swts + 320000;            // 6,400,000 (slab5 | fTb+recs | m1_cl | slab3)
    float* F     = E + 6400000;              // 1,800,000 (xpadP+wpk1f | sf_cl | q2pad)
    float* H     = F + 1800000;              // 2,700,000 (m2_cl)
    short* wp_all= (short*)(H + 2700000);    // 2,441,216 sh

    float*  slab  = E;                       // conv1: 5 slabs; later convs: 3 slabs
    short*  fT0   = (short*)E;               // 2,962,080 shorts (bf16 feats, concatenated)
    float2* recs  = (float2*)(E + 1600000);  // 480,000 f2
    int*    recn  = (int*)(E + 2560000);     // 480,000
    int*    cnts  = (int*)(E + 3040000);     //  80,000
    short*  m1_cl = (short*)E;               // 5,120,000 sh [100][100][512]
    float*  xpadP = F;                       // 1,384,448 f
    float*  wpk1f = F + 1384448;             //   409,600 f
    short*  sf_cl = (short*)F;               // 2,663,424 sh [102][102][256]
    short*  q2pad = (short*)F;               // 1,384,448 sh [104][104][128]
    short*  m2_cl = (short*)H;               // 5,326,848 sh [102][102][512]
    short*  wp_m1 = wp_all;                  // 1,179,648
    short*  wp_m2 = wp_m1 + 1179648;         //   262,144
    short*  wp_m3 = wp_m2 + 262144;          //   589,824
    short*  wp_out= wp_m3 + 589824;          //   409,600

    const dim3 blk(256);

    // ---- weight packing ----
    hipLaunchKernelGGL(pack_w1_f32, dim3(1600), blk, 0, stream, in_w, wpk1f);
    hipLaunchKernelGGL(pack_all_bf16, dim3(9536), blk, 0, stream,
                       mid_w1, mid_w2, mid_w3, out_w, wp_all);

    // ---- 1. q1 slabs = conv5x5_f32(bev_query), then qn = inorm(q1) fused ----
    hipLaunchKernelGGL(pad_xpad, dim3(5408), blk, 0, stream, bev_query, xpadP);
    hipLaunchKernelGGL(conv1_f32, dim3(4, 50, 5), blk, 0, stream, wpk1f, xpadP, slab);
    hipLaunchKernelGGL(red_norm_k<5>, dim3(128), blk, 0, stream, in_b, bev_query, slab, qn);

    // ---- 2. ref points + softmax weights + projection compaction ----
    hipLaunchKernelGGL(offsw_proj, dim3(HW), dim3(64), 0, stream,
                       qn, bev_pos, off_w, off_b, sw_w, sw_b, l2i,
                       refp, swts, recs, recn, cnts);

    // ---- 3. feature transposes -> bf16 (slab5 dead) ----
    hipLaunchKernelGGL(transpose_all, dim3(11571), blk, 0, stream,
                       feat0, feat1, feat2, feat3, fT0);

    // ---- 4. sampling -> sf_cl bf16 padded(1) ----
    hipMemsetAsync(sf_cl, 0, (size_t)2663424 * 2, stream);
    hipLaunchKernelGGL(sample_k4, dim3(HW), dim3(64), 0, stream,
                       refp, swts, recs, recn, cnts, fT0, sf_cl);

    // ---- 5. m1 = gelu(conv3x3 256->512) ----
    hipLaunchKernelGGL((mfma_conv<256, 3, 512, 1, true, 0, 100, 1>), dim3(4, 25, 4), blk, 0, stream,
                       wp_m1, sf_cl, mid_b1, nullptr, m1_cl);
    // ---- 6. m2 = gelu(conv1x1 512->512) -> padded(1) ----
    hipMemsetAsync(m2_cl, 0, (size_t)5326848 * 2, stream);
    hipLaunchKernelGGL((mfma_conv<512, 1, 512, 1, true, 1, 102, 1>), dim3(4, 25, 4), blk, 0, stream,
                       wp_m2, m1_cl, mid_b2, nullptr, m2_cl);
    // ---- 7. q2 = inorm(qn + conv3x3 512->128) ----
    hipLaunchKernelGGL((mfma_conv<512, 3, 128, 2, false, 0, 0, 3>), dim3(1, 25, 12), blk, 0, stream,
                       wp_m3, m2_cl, mid_b3, slab, nullptr);
    hipLaunchKernelGGL(red_norm_k<3>, dim3(128), blk, 0, stream, mid_b3, qn, slab, qn);
    // ---- 8. q3 = inorm(qn + conv5x5 bf16) ----
    hipLaunchKernelGGL((pad_cl_cast<128, 2>), dim3(5411), blk, 0, stream, qn, q2pad);
    hipLaunchKernelGGL((mfma_conv<128, 5, 128, 2, false, 0, 0, 3>), dim3(1, 25, 12), blk, 0, stream,
                       wp_out, q2pad, out_b, slab, nullptr);
    hipLaunchKernelGGL(red_norm_k<3>, dim3(128), blk, 0, stream, out_b, qn, slab, out);
}